// Round 12
// baseline (390.513 us; speedup 1.0000x reference)
//
#include <hip/hip_runtime.h>
#include <math.h>

#define NN 50000
#define EE 800000
#define HH 256
#define CC 64
#define NPAD 50048          // NN rounded to 128
#define NB 196              // scan blocks = ceil(NN/256)
#define QSCALE 0.09016843798f   // (1/16) * log2(e): folds 1/sqrt(H) and exp->exp2

typedef _Float16 f16x8 __attribute__((ext_vector_type(8)));
typedef _Float16 h2 __attribute__((ext_vector_type(2)));
typedef float f32x4 __attribute__((ext_vector_type(4)));

// exact tanh-gelu via sigmoid identity: 0.5x(1+tanh(z)) = x / (1 + exp(-2z))
__device__ __forceinline__ float gelu_f(float x) {
    const float A = 2.302118074f;    // 2*log2(e)*sqrt(2/pi)
    const float B = 0.1029439565f;   // A*0.044715
    float u = x * fmaf(B, x * x, A);
    float den = 1.0f + exp2f(-u);
#if __has_builtin(__builtin_amdgcn_rcpf)
    return x * __builtin_amdgcn_rcpf(den);
#else
    return x / den;
#endif
}

__device__ __forceinline__ unsigned short f2h(float x) {
    _Float16 h = (_Float16)x;
    return __builtin_bit_cast(unsigned short, h);
}

__device__ __forceinline__ float h2f_(unsigned short u) {
    return (float)__builtin_bit_cast(_Float16, u);
}

__device__ __forceinline__ unsigned rl_u(unsigned v, int l) {
#if __has_builtin(__builtin_amdgcn_readlane)
    return __builtin_amdgcn_readlane(v, l);
#else
    return __shfl((int)v, l);
#endif
}

__device__ __forceinline__ float rl_f(float v, int l) {
    return __uint_as_float(rl_u(__float_as_uint(v), l));
}

__device__ __forceinline__ void gld_lds16(const void* g, void* l) {
    __builtin_amdgcn_global_load_lds(
        (const __attribute__((address_space(1))) unsigned int*)g,
        (__attribute__((address_space(3))) unsigned int*)l,
        16, 0, 0);
}

// ---------------------------------------------------------------------------
// C[M,Nc] = act(A_f16[M,K] @ BT_f16[Nc,K]^T + bias); 128x128 tile, BK=64,
// 4 waves, 16x16x32 f16 MFMA, global_load_lds, XOR-swizzled LDS.
// STATS:  atomically accumulate per-row sum/sumsq of the output into st1/st2.
// LNFOLD: out = inv*raw - inv*mu*u[col] + bias[col], mu/inv from rs1/rs2.
// ---------------------------------------------------------------------------
template<int ACT, bool OUT_F16, bool STATS, bool LNFOLD>
__global__ __launch_bounds__(256) void mfma_gemm(
    const unsigned short* __restrict__ A,
    const unsigned short* __restrict__ BT,
    const float* __restrict__ bias,
    void* __restrict__ C,
    int M, int K, int Nc,
    float* __restrict__ st1, float* __restrict__ st2,
    const float* __restrict__ rs1, const float* __restrict__ rs2,
    const float* __restrict__ uvec)
{
    __shared__ __align__(16) unsigned char lds[32768]; // A: [0,16K), B: [16K,32K)
    const int t    = threadIdx.x;
    const int lane = t & 63;
    const int wv   = t >> 6;
    const int wr   = wv >> 1, wc = wv & 1;
    const int row0 = blockIdx.y * 128;
    const int col0 = blockIdx.x * 128;

    f32x4 acc[4][4] = {};

    const int srow  = t >> 3;               // 0..31
    const int sslot = t & 7;
    const int schunk = sslot ^ (srow & 7);  // XOR-swizzled k-chunk slot

    const unsigned short* Ab = A  + (size_t)row0 * K;
    const unsigned short* Bb = BT + (size_t)col0 * K;

    for (int k0 = 0; k0 < K; k0 += 64) {
        #pragma unroll
        for (int i = 0; i < 4; ++i)
            gld_lds16(Ab + (size_t)(i * 32 + srow) * K + k0 + schunk * 8,
                      &lds[i * 4096 + t * 16]);
        #pragma unroll
        for (int i = 0; i < 4; ++i)
            gld_lds16(Bb + (size_t)(i * 32 + srow) * K + k0 + schunk * 8,
                      &lds[16384 + i * 4096 + t * 16]);
        __syncthreads();

        #pragma unroll
        for (int kk = 0; kk < 2; ++kk) {
            f16x8 af[4], bf[4];
            #pragma unroll
            for (int m = 0; m < 4; ++m) {
                int r  = wr * 64 + m * 16 + (lane & 15);
                int ch = (kk * 4 + (lane >> 4)) ^ (r & 7);
                af[m] = *reinterpret_cast<const f16x8*>(&lds[r * 128 + ch * 16]);
            }
            #pragma unroll
            for (int n = 0; n < 4; ++n) {
                int r  = wc * 64 + n * 16 + (lane & 15);
                int ch = (kk * 4 + (lane >> 4)) ^ (r & 7);
                bf[n] = *reinterpret_cast<const f16x8*>(&lds[16384 + r * 128 + ch * 16]);
            }
            #pragma unroll
            for (int m = 0; m < 4; ++m)
                #pragma unroll
                for (int n = 0; n < 4; ++n)
                    acc[m][n] = __builtin_amdgcn_mfma_f32_16x16x32_f16(
                        af[m], bf[n], acc[m][n], 0, 0, 0);
        }
        __syncthreads();
    }

    float bv[4], uv_[4];
    #pragma unroll
    for (int n = 0; n < 4; ++n) {
        int col = col0 + wc * 64 + n * 16 + (lane & 15);
        bv[n] = bias[col];
        if (LNFOLD) uv_[n] = uvec[col];
    }

    #pragma unroll
    for (int m = 0; m < 4; ++m) {
        #pragma unroll
        for (int rg = 0; rg < 4; ++rg) {
            int row = row0 + wr * 64 + m * 16 + (lane >> 4) * 4 + rg;
            float inv = 0.f, nmu = 0.f;
            if (LNFOLD) {
                float S1 = rs1[row], S2 = rs2[row];
                float mu = S1 * (1.0f / HH);
                float var = S2 * (1.0f / HH) - mu * mu;
                inv = rsqrtf(var + 1e-5f);
                nmu = inv * mu;
            }
            float s1l = 0.f, s2l = 0.f;
            #pragma unroll
            for (int n = 0; n < 4; ++n) {
                float v;
                if (LNFOLD) v = fmaf(inv, acc[m][n][rg], fmaf(-nmu, uv_[n], bv[n]));
                else        v = acc[m][n][rg] + bv[n];
                if (ACT) v = gelu_f(v);
                if (STATS) { s1l += v; s2l += v * v; }
                if (row < M) {
                    int col = col0 + wc * 64 + n * 16 + (lane & 15);
                    if (OUT_F16) ((unsigned short*)C)[(size_t)row * Nc + col] = f2h(v);
                    else         ((float*)C)[(size_t)row * Nc + col] = v;
                }
            }
            if (STATS) {
                #pragma unroll
                for (int o = 1; o < 16; o <<= 1) {
                    s1l += __shfl_xor(s1l, o);
                    s2l += __shfl_xor(s2l, o);
                }
                if ((lane & 15) == 0 && row < M) {
                    atomicAdd(&st1[row], s1l);
                    atomicAdd(&st2[row], s2l);
                }
            }
        }
    }
}

// ---------------------------------------------------------------------------
// prep mega-kernel: f2h(embedding), f2h(scores), W1T, W2T, WlrT (g-folded,
// q-half scaled by QSCALE), k2 table, u/v fold vectors — one launch.
// ---------------------------------------------------------------------------
#define PB0 12500
#define PB1 (PB0 + 3125)
#define PB2 (PB1 + 1024)
#define PB3 (PB2 + 1024)
#define PB4 (PB3 + 256)
#define PB5 (PB4 + 256)
#define PB6 (PB5 + 3)
#define PB7 (PB6 + 2)
__global__ __launch_bounds__(256) void prep_kernel(
    const float* __restrict__ embedding, const float* __restrict__ scores,
    const float* __restrict__ W1, const float* __restrict__ W2,
    const float* __restrict__ Wl, const float* __restrict__ Wr,
    const float* __restrict__ ln_g, const float* __restrict__ ln_b,
    const float* __restrict__ bl, const float* __restrict__ br,
    const float* __restrict__ We, const float* __restrict__ be,
    const float* __restrict__ emb_table,
    unsigned short* __restrict__ embA, unsigned short* __restrict__ scoresb,
    unsigned short* __restrict__ W1T, unsigned short* __restrict__ W2T,
    unsigned short* __restrict__ WlrT, unsigned short* __restrict__ k2t,
    float* __restrict__ uvec, float* __restrict__ vvec)
{
    const int gb = blockIdx.x, t = threadIdx.x;
    if (gb < PB0) {
        int i = gb * 256 + t;
        float4 v = reinterpret_cast<const float4*>(embedding)[i];
        ushort4 o; o.x = f2h(v.x); o.y = f2h(v.y); o.z = f2h(v.z); o.w = f2h(v.w);
        reinterpret_cast<ushort4*>(embA)[i] = o;
    } else if (gb < PB1) {
        int i = (gb - PB0) * 256 + t;
        float4 v = reinterpret_cast<const float4*>(scores)[i];
        ushort4 o; o.x = f2h(v.x); o.y = f2h(v.y); o.z = f2h(v.z); o.w = f2h(v.w);
        reinterpret_cast<ushort4*>(scoresb)[i] = o;
    } else if (gb < PB2) {
        int o = (gb - PB1) * 256 + t;
        int c = o >> 8, r = o & 255;
        W1T[o] = f2h(W1[r * 1024 + c]);
    } else if (gb < PB3) {
        int o = (gb - PB2) * 256 + t;
        int c = o >> 10, r = o & 1023;
        W2T[o] = f2h(W2[r * 256 + c]);
    } else if (gb < PB4) {
        int o = (gb - PB3) * 256 + t;
        int c = o >> 8, r = o & 255;
        WlrT[o] = f2h(Wl[r * 256 + c] * ln_g[r] * QSCALE);
    } else if (gb < PB5) {
        int o = (gb - PB4) * 256 + t;
        int c = o >> 8, r = o & 255;
        WlrT[65536 + o] = f2h(Wr[r * 256 + c] * ln_g[r]);
    } else if (gb < PB6) {
        int ty = gb - PB5;
        float a = be[t];
        #pragma unroll
        for (int f = 0; f < 20; ++f)
            a += gelu_f(emb_table[ty * 20 + f]) * We[f * 256 + t];
        k2t[ty * 256 + t] = f2h(a);
    } else {
        int c = (gb - PB6) * 256 + t;
        int cc = c & 255;
        const float* W = (c < 256) ? Wl : Wr;
        float u = 0.f, v = 0.f;
        for (int j = 0; j < 256; ++j) {
            float w = W[j * 256 + cc];
            u += ln_g[j] * w;
            v += ln_b[j] * w;
        }
        float sc = (c < 256) ? QSCALE : 1.0f;
        uvec[c] = u * sc;
        vvec[c] = (v + ((c < 256) ? bl[cc] : br[cc])) * sc;
    }
}

// ---- CSR build ----
__global__ void hist_kernel(const int* __restrict__ dst, int* __restrict__ cnt)
{
    int e = blockIdx.x * 256 + threadIdx.x;
    if (e < EE) atomicAdd(&cnt[dst[e]], 1);
}

__global__ __launch_bounds__(256) void scan_part(
    const int* __restrict__ cnt, int* __restrict__ off, int* __restrict__ bsum)
{
    int b = blockIdx.x, t = threadIdx.x;
    int idx = b * 256 + t;
    int v = (idx < NN) ? cnt[idx] : 0;
    int inc = v;
    #pragma unroll
    for (int o = 1; o < 64; o <<= 1) {
        int u = __shfl_up(inc, o);
        if ((t & 63) >= o) inc += u;
    }
    __shared__ int wt[4];
    if ((t & 63) == 63) wt[t >> 6] = inc;
    __syncthreads();
    int wo = 0;
    #pragma unroll
    for (int w = 0; w < 4; ++w) if (w < (t >> 6)) wo += wt[w];
    if (idx < NN) off[idx] = wo + inc - v;
    if (t == 255) bsum[b] = wo + inc;
}

__global__ __launch_bounds__(256) void scan_sums(int* __restrict__ bsum)
{
    int t = threadIdx.x;
    int v = (t < NB) ? bsum[t] : 0;
    int inc = v;
    #pragma unroll
    for (int o = 1; o < 64; o <<= 1) {
        int u = __shfl_up(inc, o);
        if ((t & 63) >= o) inc += u;
    }
    __shared__ int wt[4];
    if ((t & 63) == 63) wt[t >> 6] = inc;
    __syncthreads();
    int wo = 0;
    #pragma unroll
    for (int w = 0; w < 4; ++w) if (w < (t >> 6)) wo += wt[w];
    if (t < NB) bsum[t] = wo + inc - v;
}

__global__ void scan_add(int* __restrict__ off, const int* __restrict__ bsum,
                         int* __restrict__ cur)
{
    int b = blockIdx.x, t = threadIdx.x;
    int idx = b * 256 + t;
    if (idx < NN) {
        int o = off[idx] + bsum[b];
        off[idx] = o;
        cur[idx] = o;
    }
    if (idx == 0) off[NN] = EE;
}

// pack entry = (src << 10) | ty  -> byte offset of the qk row, type in low bits
__global__ void fill_kernel(const int* __restrict__ src, const int* __restrict__ dst,
                            const int* __restrict__ typ, int* __restrict__ cur,
                            unsigned int* __restrict__ pack)
{
    int e = blockIdx.x * 256 + threadIdx.x;
    if (e < 16) pack[EE + e] = 0;
    if (e >= EE) return;
    int pos = atomicAdd(&cur[dst[e]], 1);
    pack[pos] = ((unsigned int)src[e] << 10) | (unsigned int)typ[e];
}

// ---------------------------------------------------------------------------
// fused per-dst attention v5: one wave per node; 16 edges per MFMA batch.
// A-frag = 16 gathered k1 rows (row=lane&15, k=(lane>>4)*8), B-frag = q[d]
// broadcast to all 16 cols. 8 chained mfma_16x16x32_f16 give all 16 dots.
// qe[0..2] via the same MFMA trick with A rows = k2t. Batched online softmax
// (4 exp2 + 2 shfl per lane per 16 edges); score accumulation via readlane-
// broadcast weights (SGPR) + per-edge gather.
// ---------------------------------------------------------------------------
__global__ __launch_bounds__(256) void fused_edge_kernel(
    const unsigned short* __restrict__ qk,      // f16 [NPAD][512]: [q*QSCALE | k1]
    const unsigned short* __restrict__ k2t,     // f16 [3][256]
    const int* __restrict__ off, const unsigned int* __restrict__ pack,
    const unsigned short* __restrict__ scoresb, // f16 [NN][64]
    float* __restrict__ out)
{
    const int t = threadIdx.x, lane = t & 63;
    const int grp = lane >> 4;          // 0..3: k-slice group / edge-quad owner
    const int col = lane & 15;          // edge slot this lane gathers for A
    const int d = blockIdx.x * 4 + (t >> 6);
    if (d >= NN) return;
    const int beg = off[d], end = off[d + 1];
    if (beg == end) { out[(size_t)d * CC + lane] = 0.f; return; }

    const char* qkb = (const char*)qk;

    // B-fragments: q[d] in MFMA-B layout (identical across the 16 cols)
    uint4 bq[8];
    #pragma unroll
    for (int j = 0; j < 8; ++j)
        bq[j] = *reinterpret_cast<const uint4*>(
            qkb + (size_t)d * 1024 + j * 64 + grp * 16);

    // qe[ty] = q . k2t[ty] via one MFMA batch (A rows 0..2 = k2t, rest ignored)
    float qe0, qe1, qe2;
    {
        int rA = (col < 3) ? col : 0;
        const char* kb = (const char*)k2t + rA * 512;
        f32x4 dq = {};
        #pragma unroll
        for (int j = 0; j < 8; ++j) {
            uint4 av = *reinterpret_cast<const uint4*>(kb + j * 64 + grp * 16);
            dq = __builtin_amdgcn_mfma_f32_16x16x32_f16(
                __builtin_bit_cast(f16x8, av), __builtin_bit_cast(f16x8, bq[j]),
                dq, 0, 0, 0);
        }
        // D row t lives in lane 0's reg t (col 0, grp 0)
        qe0 = rl_f(dq[0], 0);
        qe1 = rl_f(dq[1], 0);
        qe2 = rl_f(dq[2], 0);
    }

    float m = -INFINITY, s = 0.f, acc = 0.f;

    for (int i = beg; i < end; i += 16) {
        const int nv = end - i;                         // valid edges this batch
        // A gather: this lane fetches k1 row of edge `col`
        unsigned pkc = pack[i + ((col < nv) ? col : 0)];
        const char* arow = qkb + (pkc & ~3u) + 512;
        f32x4 dd = {};
        #pragma unroll
        for (int j = 0; j < 8; ++j) {
            uint4 av = *reinterpret_cast<const uint4*>(arow + j * 64 + grp * 16);
            dd = __builtin_amdgcn_mfma_f32_16x16x32_f16(
                __builtin_bit_cast(f16x8, av), __builtin_bit_cast(f16x8, bq[j]),
                dd, 0, 0, 0);
        }
        // this lane's 4 edges: e = grp*4 + r  (D row = grp*4 + r, any col)
        float a[4]; unsigned pkr[4];
        #pragma unroll
        for (int r = 0; r < 4; ++r) {
            int e = grp * 4 + r;
            unsigned pk = pack[i + ((e < nv) ? e : 0)];
            pkr[r] = pk;
            int ty = pk & 3;
            float qe = (ty == 0) ? qe0 : (ty == 1) ? qe1 : qe2;
            a[r] = (e < nv) ? dd[r] + qe : -INFINITY;
        }
        float bm = fmaxf(fmaxf(a[0], a[1]), fmaxf(a[2], a[3]));
        bm = fmaxf(bm, __shfl_xor(bm, 16));
        bm = fmaxf(bm, __shfl_xor(bm, 32));
        float nm = fmaxf(m, bm);
        float c_ = exp2f(m - nm);                       // first batch: 0
        float w[4];
        #pragma unroll
        for (int r = 0; r < 4; ++r) w[r] = exp2f(a[r] - nm);
        float sp = (w[0] + w[1]) + (w[2] + w[3]);
        sp += __shfl_xor(sp, 16);
        sp += __shfl_xor(sp, 32);

        float partial = 0.f;
        #pragma unroll
        for (int e = 0; e < 16; ++e) {
            float    we  = rl_f(w[e & 3],   (e >> 2) * 16);   // SGPR broadcast
            unsigned pke = rl_u(pkr[e & 3], (e >> 2) * 16);
            float sc = h2f_(scoresb[((pke & ~3u) >> 4) + lane]);
            partial = fmaf(we, sc, partial);
        }
        s = s * c_ + sp;
        acc = fmaf(acc, c_, partial);
        m = nm;
    }
    out[(size_t)d * CC + lane] = acc / s;
}

extern "C" void kernel_launch(void* const* d_in, const int* in_sizes, int n_in,
                              void* d_out, int out_size, void* d_ws, size_t ws_size,
                              hipStream_t stream) {
    const float* embedding = (const float*)d_in[0];
    const float* scores    = (const float*)d_in[1];
    const int*   src       = (const int*)d_in[2];
    const int*   dst       = (const int*)d_in[3];
    const int*   typ       = (const int*)d_in[4];
    const float* W1  = (const float*)d_in[5];
    const float* b1  = (const float*)d_in[6];
    const float* W2  = (const float*)d_in[7];
    const float* b2  = (const float*)d_in[8];
    const float* ln_g = (const float*)d_in[9];
    const float* ln_b = (const float*)d_in[10];
    const float* Wl  = (const float*)d_in[11];
    const float* bl  = (const float*)d_in[12];
    const float* Wr  = (const float*)d_in[13];
    const float* br  = (const float*)d_in[14];
    const float* We  = (const float*)d_in[15];
    const float* be  = (const float*)d_in[16];
    const float* emb_table = (const float*)d_in[17];
    float* out = (float*)d_out;
    (void)in_sizes; (void)n_in; (void)out_size; (void)ws_size;

    // ---- workspace carve-up (256-aligned chunks) ----
    char* w = (char*)d_ws;
    auto take = [&](size_t bytes) {
        char* p = w;
        w += (bytes + 255) & ~(size_t)255;
        return p;
    };
    unsigned short* embA = (unsigned short*)take((size_t)NPAD * HH * 2);
    unsigned short* hpre = (unsigned short*)take((size_t)NPAD * HH * 2);
    // BIG buffer: Gch [NPAD][1024] f16 during the MLP; first half reused as
    // qk [NPAD][512] f16 (Gch dead once GEMM2 reads it).
    unsigned short* Gch  = (unsigned short*)take((size_t)NPAD * 1024 * 2);
    unsigned short* qk   = Gch;
    unsigned short* W1T  = (unsigned short*)take((size_t)4 * HH * HH * 2);
    unsigned short* W2T  = (unsigned short*)take((size_t)HH * 4 * HH * 2);
    unsigned short* WlrT = (unsigned short*)take((size_t)512 * HH * 2);
    unsigned short* k2t  = (unsigned short*)take(2048);
    unsigned short* scoresb = (unsigned short*)take((size_t)NN * CC * 2);
    float*          uvec = (float*)take(512 * 4);
    float*          vvec = (float*)take(512 * 4);
    int*            cnt  = (int*)take((size_t)NPAD * 4);
    float*          st1  = (float*)take((size_t)NPAD * 4);
    float*          st2  = (float*)take((size_t)NPAD * 4);
    int*            offb = (int*)take((size_t)(NN + 1) * 4);
    int*            cur  = (int*)take((size_t)NN * 4);
    int*            bsum = (int*)take(256 * 4);
    unsigned int*   pack = (unsigned int*)take((size_t)EE * 4 + 64);

    hipMemsetAsync(cnt, 0, (size_t)3 * NPAD * 4, stream);

    // ---- one prep launch ----
    prep_kernel<<<PB7, 256, 0, stream>>>(
        embedding, scores, W1, W2, Wl, Wr, ln_g, ln_b, bl, br, We, be, emb_table,
        embA, scoresb, W1T, W2T, WlrT, k2t, uvec, vvec);

    // ---- CSR build ----
    hist_kernel<<<(EE + 255) / 256, 256, 0, stream>>>(dst, cnt);
    scan_part<<<NB, 256, 0, stream>>>(cnt, offb, bsum);
    scan_sums<<<1, 256, 0, stream>>>(bsum);
    scan_add<<<NB, 256, 0, stream>>>(offb, bsum, cur);
    fill_kernel<<<(EE + 255) / 256, 256, 0, stream>>>(src, dst, typ, cur, pack);

    // ---- MLP (full-grid): hpre = gelu(X@W1+b1)@W2+b2, stats fused ----
    dim3 g1(4 * HH / 128, NPAD / 128);
    mfma_gemm<1, true, false, false><<<g1, 256, 0, stream>>>(
        embA, W1T, b1, Gch, NN, HH, 4 * HH,
        nullptr, nullptr, nullptr, nullptr, nullptr);
    dim3 g2(HH / 128, NPAD / 128);
    mfma_gemm<0, true, true, false><<<g2, 256, 0, stream>>>(
        Gch, W2T, b2, hpre, NN, 4 * HH, HH,
        st1, st2, nullptr, nullptr, nullptr);

    // ---- q|k1 projection with fused LayerNorm (qk aliases dead Gch) ----
    dim3 gq(512 / 128, NPAD / 128);
    mfma_gemm<0, true, false, true><<<gq, 256, 0, stream>>>(
        hpre, WlrT, vvec, qk, NN, HH, 512,
        nullptr, nullptr, st1, st2, uvec);

    // ---- fused edge phase (MFMA-batched) ----
    fused_edge_kernel<<<(NN + 3) / 4, 256, 0, stream>>>(qk, k2t, offb, pack, scoresb, out);
}

// Round 13
// 384.747 us; speedup vs baseline: 1.0150x; 1.0150x over previous
//
#include <hip/hip_runtime.h>
#include <math.h>

#define NN 50000
#define EE 800000
#define HH 256
#define CC 64
#define NPAD 50048          // NN rounded to 128
#define NB 196              // scan blocks = ceil(NN/256)
#define QSCALE 0.09016843798f   // (1/16) * log2(e): folds 1/sqrt(H) and exp->exp2

typedef _Float16 f16x8 __attribute__((ext_vector_type(8)));
typedef _Float16 h2 __attribute__((ext_vector_type(2)));
typedef float f32x4 __attribute__((ext_vector_type(4)));

// exact tanh-gelu via sigmoid identity: 0.5x(1+tanh(z)) = x / (1 + exp(-2z))
__device__ __forceinline__ float gelu_f(float x) {
    const float A = 2.302118074f;    // 2*log2(e)*sqrt(2/pi)
    const float B = 0.1029439565f;   // A*0.044715
    float u = x * fmaf(B, x * x, A);
    float den = 1.0f + exp2f(-u);
#if __has_builtin(__builtin_amdgcn_rcpf)
    return x * __builtin_amdgcn_rcpf(den);
#else
    return x / den;
#endif
}

__device__ __forceinline__ unsigned short f2h(float x) {
    _Float16 h = (_Float16)x;
    return __builtin_bit_cast(unsigned short, h);
}

__device__ __forceinline__ float h2f_(unsigned short u) {
    return (float)__builtin_bit_cast(_Float16, u);
}

__device__ __forceinline__ h2 u2h2(unsigned int u) {
    return __builtin_bit_cast(h2, u);
}

// float -> OCP fp8 e4m3fn (RNE via f16; flush |x|<2^-6 to 0; clamp to 448)
__device__ __forceinline__ unsigned char f2fp8(float v) {
    unsigned short h = f2h(v);
    unsigned s = (h >> 8) & 0x80u;
    int E = (h >> 10) & 31;
    unsigned M = h & 1023u;
    if (E <= 8) return (unsigned char)s;          // tiny -> signed zero
    unsigned m3 = M >> 7, rem = M & 127u;
    m3 += (rem > 64u) || (rem == 64u && (m3 & 1u));
    if (m3 == 8u) { m3 = 0u; ++E; }
    if (E > 23) { E = 23; m3 = 6u; }              // clamp to 448
    if (E == 23 && m3 == 7u) m3 = 6u;             // avoid NaN encoding
    return (unsigned char)(s | ((unsigned)(E - 8) << 3) | m3);
}

// 4x fp8 e4m3 (packed in u32) -> 4x f32
__device__ __forceinline__ void fp8x4_to_f32(unsigned w, float* o) {
#if __has_builtin(__builtin_amdgcn_cvt_pk_f32_fp8)
    auto lo = __builtin_amdgcn_cvt_pk_f32_fp8(w, false);
    auto hi = __builtin_amdgcn_cvt_pk_f32_fp8(w, true);
    o[0] = lo[0]; o[1] = lo[1]; o[2] = hi[0]; o[3] = hi[1];
#else
    #pragma unroll
    for (int i = 0; i < 4; ++i) {
        unsigned u8 = (w >> (8 * i)) & 255u;
        unsigned short hb = (u8 & 0x7Fu)
            ? (unsigned short)(((u8 & 0x80u) << 8) | (((u8 & 0x7Fu) << 7) + 0x2000u))
            : (unsigned short)(u8 << 8);
        o[i] = h2f_(hb);
    }
#endif
}

__device__ __forceinline__ void gld_lds16(const void* g, void* l) {
    __builtin_amdgcn_global_load_lds(
        (const __attribute__((address_space(1))) unsigned int*)g,
        (__attribute__((address_space(3))) unsigned int*)l,
        16, 0, 0);
}

// ---------------------------------------------------------------------------
// C[M,Nc] = act(A_f16[M,K] @ BT_f16[Nc,K]^T + bias); 128x128 tile, BK=64,
// 4 waves, 16x16x32 f16 MFMA, global_load_lds, XOR-swizzled LDS.
// OUTMODE: 0 = f32 C, 1 = f16 C, 2 = split (col<256 -> f16 q-buffer stride
//          256; col>=256 -> fp8 e4m3 into kout stride 256).
// STATS:  per-row sum/sumsq atomics into st1/st2.
// LNFOLD: out = inv*raw - inv*mu*u[col] + bias[col], mu/inv from rs1/rs2.
// ---------------------------------------------------------------------------
template<int ACT, int OUTMODE, bool STATS, bool LNFOLD>
__global__ __launch_bounds__(256) void mfma_gemm(
    const unsigned short* __restrict__ A,
    const unsigned short* __restrict__ BT,
    const float* __restrict__ bias,
    void* __restrict__ C,
    unsigned char* __restrict__ kout,
    int M, int K, int Nc,
    float* __restrict__ st1, float* __restrict__ st2,
    const float* __restrict__ rs1, const float* __restrict__ rs2,
    const float* __restrict__ uvec)
{
    __shared__ __align__(16) unsigned char lds[32768]; // A: [0,16K), B: [16K,32K)
    const int t    = threadIdx.x;
    const int lane = t & 63;
    const int wv   = t >> 6;
    const int wr   = wv >> 1, wc = wv & 1;
    const int row0 = blockIdx.y * 128;
    const int col0 = blockIdx.x * 128;

    f32x4 acc[4][4] = {};

    const int srow  = t >> 3;               // 0..31
    const int sslot = t & 7;
    const int schunk = sslot ^ (srow & 7);  // XOR-swizzled k-chunk slot

    const unsigned short* Ab = A  + (size_t)row0 * K;
    const unsigned short* Bb = BT + (size_t)col0 * K;

    for (int k0 = 0; k0 < K; k0 += 64) {
        #pragma unroll
        for (int i = 0; i < 4; ++i)
            gld_lds16(Ab + (size_t)(i * 32 + srow) * K + k0 + schunk * 8,
                      &lds[i * 4096 + t * 16]);
        #pragma unroll
        for (int i = 0; i < 4; ++i)
            gld_lds16(Bb + (size_t)(i * 32 + srow) * K + k0 + schunk * 8,
                      &lds[16384 + i * 4096 + t * 16]);
        __syncthreads();

        #pragma unroll
        for (int kk = 0; kk < 2; ++kk) {
            f16x8 af[4], bf[4];
            #pragma unroll
            for (int m = 0; m < 4; ++m) {
                int r  = wr * 64 + m * 16 + (lane & 15);
                int ch = (kk * 4 + (lane >> 4)) ^ (r & 7);
                af[m] = *reinterpret_cast<const f16x8*>(&lds[r * 128 + ch * 16]);
            }
            #pragma unroll
            for (int n = 0; n < 4; ++n) {
                int r  = wc * 64 + n * 16 + (lane & 15);
                int ch = (kk * 4 + (lane >> 4)) ^ (r & 7);
                bf[n] = *reinterpret_cast<const f16x8*>(&lds[16384 + r * 128 + ch * 16]);
            }
            #pragma unroll
            for (int m = 0; m < 4; ++m)
                #pragma unroll
                for (int n = 0; n < 4; ++n)
                    acc[m][n] = __builtin_amdgcn_mfma_f32_16x16x32_f16(
                        af[m], bf[n], acc[m][n], 0, 0, 0);
        }
        __syncthreads();
    }

    float bv[4], uv_[4];
    #pragma unroll
    for (int n = 0; n < 4; ++n) {
        int col = col0 + wc * 64 + n * 16 + (lane & 15);
        bv[n] = bias[col];
        if (LNFOLD) uv_[n] = uvec[col];
    }

    #pragma unroll
    for (int m = 0; m < 4; ++m) {
        #pragma unroll
        for (int rg = 0; rg < 4; ++rg) {
            int row = row0 + wr * 64 + m * 16 + (lane >> 4) * 4 + rg;
            float inv = 0.f, nmu = 0.f;
            if (LNFOLD) {
                float S1 = rs1[row], S2 = rs2[row];
                float mu = S1 * (1.0f / HH);
                float var = S2 * (1.0f / HH) - mu * mu;
                inv = rsqrtf(var + 1e-5f);
                nmu = inv * mu;
            }
            float s1l = 0.f, s2l = 0.f;
            #pragma unroll
            for (int n = 0; n < 4; ++n) {
                float v;
                if (LNFOLD) v = fmaf(inv, acc[m][n][rg], fmaf(-nmu, uv_[n], bv[n]));
                else        v = acc[m][n][rg] + bv[n];
                if (ACT) v = gelu_f(v);
                if (STATS) { s1l += v; s2l += v * v; }
                if (row < M) {
                    int col = col0 + wc * 64 + n * 16 + (lane & 15);
                    if (OUTMODE == 0)
                        ((float*)C)[(size_t)row * Nc + col] = v;
                    else if (OUTMODE == 1)
                        ((unsigned short*)C)[(size_t)row * Nc + col] = f2h(v);
                    else {
                        if (col < 256)
                            ((unsigned short*)C)[(size_t)row * 256 + col] = f2h(v);
                        else
                            kout[(size_t)row * 256 + (col - 256)] = f2fp8(v);
                    }
                }
            }
            if (STATS) {
                #pragma unroll
                for (int o = 1; o < 16; o <<= 1) {
                    s1l += __shfl_xor(s1l, o);
                    s2l += __shfl_xor(s2l, o);
                }
                if ((lane & 15) == 0 && row < M) {
                    atomicAdd(&st1[row], s1l);
                    atomicAdd(&st2[row], s2l);
                }
            }
        }
    }
}

// ---------------------------------------------------------------------------
// prep mega-kernel: f2h(embedding), f2h(scores), W1T, W2T, WlrT (g-folded,
// q-half scaled by QSCALE), k2 table, u/v fold vectors — one launch.
// ---------------------------------------------------------------------------
#define PB0 12500
#define PB1 (PB0 + 3125)
#define PB2 (PB1 + 1024)
#define PB3 (PB2 + 1024)
#define PB4 (PB3 + 256)
#define PB5 (PB4 + 256)
#define PB6 (PB5 + 3)
#define PB7 (PB6 + 2)
__global__ __launch_bounds__(256) void prep_kernel(
    const float* __restrict__ embedding, const float* __restrict__ scores,
    const float* __restrict__ W1, const float* __restrict__ W2,
    const float* __restrict__ Wl, const float* __restrict__ Wr,
    const float* __restrict__ ln_g, const float* __restrict__ ln_b,
    const float* __restrict__ bl, const float* __restrict__ br,
    const float* __restrict__ We, const float* __restrict__ be,
    const float* __restrict__ emb_table,
    unsigned short* __restrict__ embA, unsigned short* __restrict__ scoresb,
    unsigned short* __restrict__ W1T, unsigned short* __restrict__ W2T,
    unsigned short* __restrict__ WlrT, unsigned short* __restrict__ k2t,
    float* __restrict__ uvec, float* __restrict__ vvec)
{
    const int gb = blockIdx.x, t = threadIdx.x;
    if (gb < PB0) {
        int i = gb * 256 + t;
        float4 v = reinterpret_cast<const float4*>(embedding)[i];
        ushort4 o; o.x = f2h(v.x); o.y = f2h(v.y); o.z = f2h(v.z); o.w = f2h(v.w);
        reinterpret_cast<ushort4*>(embA)[i] = o;
    } else if (gb < PB1) {
        int i = (gb - PB0) * 256 + t;
        float4 v = reinterpret_cast<const float4*>(scores)[i];
        ushort4 o; o.x = f2h(v.x); o.y = f2h(v.y); o.z = f2h(v.z); o.w = f2h(v.w);
        reinterpret_cast<ushort4*>(scoresb)[i] = o;
    } else if (gb < PB2) {
        int o = (gb - PB1) * 256 + t;
        int c = o >> 8, r = o & 255;
        W1T[o] = f2h(W1[r * 1024 + c]);
    } else if (gb < PB3) {
        int o = (gb - PB2) * 256 + t;
        int c = o >> 10, r = o & 1023;
        W2T[o] = f2h(W2[r * 256 + c]);
    } else if (gb < PB4) {
        int o = (gb - PB3) * 256 + t;
        int c = o >> 8, r = o & 255;
        WlrT[o] = f2h(Wl[r * 256 + c] * ln_g[r] * QSCALE);
    } else if (gb < PB5) {
        int o = (gb - PB4) * 256 + t;
        int c = o >> 8, r = o & 255;
        WlrT[65536 + o] = f2h(Wr[r * 256 + c] * ln_g[r]);
    } else if (gb < PB6) {
        int ty = gb - PB5;
        float a = be[t];
        #pragma unroll
        for (int f = 0; f < 20; ++f)
            a += gelu_f(emb_table[ty * 20 + f]) * We[f * 256 + t];
        k2t[ty * 256 + t] = f2h(a);
    } else {
        int c = (gb - PB6) * 256 + t;
        int cc = c & 255;
        const float* W = (c < 256) ? Wl : Wr;
        float u = 0.f, v = 0.f;
        for (int j = 0; j < 256; ++j) {
            float w = W[j * 256 + cc];
            u += ln_g[j] * w;
            v += ln_b[j] * w;
        }
        float sc = (c < 256) ? QSCALE : 1.0f;
        uvec[c] = u * sc;
        vvec[c] = (v + ((c < 256) ? bl[cc] : br[cc])) * sc;
    }
}

// ---- CSR build ----
__global__ void hist_kernel(const int* __restrict__ dst, int* __restrict__ cnt)
{
    int e = blockIdx.x * 256 + threadIdx.x;
    if (e < EE) atomicAdd(&cnt[dst[e]], 1);
}

__global__ __launch_bounds__(256) void scan_part(
    const int* __restrict__ cnt, int* __restrict__ off, int* __restrict__ bsum)
{
    int b = blockIdx.x, t = threadIdx.x;
    int idx = b * 256 + t;
    int v = (idx < NN) ? cnt[idx] : 0;
    int inc = v;
    #pragma unroll
    for (int o = 1; o < 64; o <<= 1) {
        int u = __shfl_up(inc, o);
        if ((t & 63) >= o) inc += u;
    }
    __shared__ int wt[4];
    if ((t & 63) == 63) wt[t >> 6] = inc;
    __syncthreads();
    int wo = 0;
    #pragma unroll
    for (int w = 0; w < 4; ++w) if (w < (t >> 6)) wo += wt[w];
    if (idx < NN) off[idx] = wo + inc - v;
    if (t == 255) bsum[b] = wo + inc;
}

__global__ __launch_bounds__(256) void scan_sums(int* __restrict__ bsum)
{
    int t = threadIdx.x;
    int v = (t < NB) ? bsum[t] : 0;
    int inc = v;
    #pragma unroll
    for (int o = 1; o < 64; o <<= 1) {
        int u = __shfl_up(inc, o);
        if ((t & 63) >= o) inc += u;
    }
    __shared__ int wt[4];
    if ((t & 63) == 63) wt[t >> 6] = inc;
    __syncthreads();
    int wo = 0;
    #pragma unroll
    for (int w = 0; w < 4; ++w) if (w < (t >> 6)) wo += wt[w];
    if (t < NB) bsum[t] = wo + inc - v;
}

__global__ void scan_add(int* __restrict__ off, const int* __restrict__ bsum,
                         int* __restrict__ cur)
{
    int b = blockIdx.x, t = threadIdx.x;
    int idx = b * 256 + t;
    if (idx < NN) {
        int o = off[idx] + bsum[b];
        off[idx] = o;
        cur[idx] = o;
    }
    if (idx == 0) off[NN] = EE;
}

// pack entry = (src << 8) | ty  -> byte offset of the fp8 k-row, type in low bits
__global__ void fill_kernel(const int* __restrict__ src, const int* __restrict__ dst,
                            const int* __restrict__ typ, int* __restrict__ cur,
                            unsigned int* __restrict__ pack)
{
    int e = blockIdx.x * 256 + threadIdx.x;
    if (e < 16) pack[EE + e] = 0;
    if (e >= EE) return;
    int pos = atomicAdd(&cur[dst[e]], 1);
    pack[pos] = ((unsigned int)src[e] << 8) | (unsigned int)typ[e];
}

// ---------------------------------------------------------------------------
// fused per-dst attention (R11 structure; k1 gathers in fp8 e4m3):
// one wave per node; 2 edges in flight, shared 32-lane dot/reduce,
// exp2-domain online softmax, qe prologue, depth-1 prefetch.
// ---------------------------------------------------------------------------
__global__ __launch_bounds__(256) void fused_edge_kernel(
    const unsigned short* __restrict__ qbuf,    // f16 [NPAD][256]: q*QSCALE
    const unsigned char* __restrict__ k8,       // fp8 [NPAD][256]: k1 (g-folded)
    const unsigned short* __restrict__ k2t,     // f16 [3][256]
    const int* __restrict__ off, const unsigned int* __restrict__ pack,
    const unsigned short* __restrict__ scoresb, // f16 [NN][64]
    float* __restrict__ out)
{
    const int t = threadIdx.x, lane = t & 63;
    const int sub = lane & 31;
    const int g = lane >> 5;
    const int d = blockIdx.x * 4 + (t >> 6);
    if (d >= NN) return;
    const int beg = off[d], end = off[d + 1];
    if (beg == end) { out[(size_t)d * CC + lane] = 0.f; return; }

    // q slice: 8 f16 at dims [sub*8, sub*8+8) (duplicated across wave halves)
    uint4 qv = *reinterpret_cast<const uint4*>(
        (const char*)qbuf + (size_t)d * 512 + sub * 16);
    h2 q0 = u2h2(qv.x), q1 = u2h2(qv.y), q2 = u2h2(qv.z), q3 = u2h2(qv.w);
    float qf[8];
    qf[0] = (float)q0[0]; qf[1] = (float)q0[1];
    qf[2] = (float)q1[0]; qf[3] = (float)q1[1];
    qf[4] = (float)q2[0]; qf[5] = (float)q2[1];
    qf[6] = (float)q3[0]; qf[7] = (float)q3[1];

    // qe[ty] = q . k2t[ty] (f16 path, k2t exact)
    float qe0, qe1, qe2;
    {
        uint4 k0v = *reinterpret_cast<const uint4*>((const char*)k2t + 0 * 512 + sub * 16);
        uint4 k1v = *reinterpret_cast<const uint4*>((const char*)k2t + 1 * 512 + sub * 16);
        uint4 k2v = *reinterpret_cast<const uint4*>((const char*)k2t + 2 * 512 + sub * 16);
        auto dot16 = [&](uint4 kv) {
            h2 p = q0 * u2h2(kv.x) + q1 * u2h2(kv.y) + q2 * u2h2(kv.z) + q3 * u2h2(kv.w);
            return (float)p[0] + (float)p[1];
        };
        qe0 = dot16(k0v); qe1 = dot16(k1v); qe2 = dot16(k2v);
        #pragma unroll
        for (int o = 1; o < 32; o <<= 1) {
            qe0 += __shfl_xor(qe0, o);
            qe1 += __shfl_xor(qe1, o);
            qe2 += __shfl_xor(qe2, o);
        }
    }
    auto qsel = [&](unsigned pk) {
        int ty = pk & 3;
        return (ty == 0) ? qe0 : (ty == 1) ? qe1 : qe2;
    };
    auto dot8 = [&](uint2 kv) {
        float kf[8];
        fp8x4_to_f32(kv.x, kf);
        fp8x4_to_f32(kv.y, kf + 4);
        float u0 = fmaf(qf[1], kf[1], qf[0] * kf[0]);
        float u1 = fmaf(qf[3], kf[3], qf[2] * kf[2]);
        float u2 = fmaf(qf[5], kf[5], qf[4] * kf[4]);
        float u3 = fmaf(qf[7], kf[7], qf[6] * kf[6]);
        return (u0 + u1) + (u2 + u3);
    };

    // prologue: pair {beg, beg+1}
    unsigned pkA = pack[beg], pkB = pack[beg + 1];
    uint2 kv = *reinterpret_cast<const uint2*>(k8 + ((g ? pkB : pkA) & ~3u) + sub * 8);
    float scA = h2f_(scoresb[((pkA & ~3u) >> 2) + lane]);
    float scB = h2f_(scoresb[((pkB & ~3u) >> 2) + lane]);

    float m = -INFINITY, s = 0.f, acc = 0.f;

    for (int i = beg; i < end; i += 2) {
        int inext = (i + 2 < end) ? i + 2 : i;
        unsigned npA = pack[inext], npB = pack[inext + 1];
        uint2 nkv = *reinterpret_cast<const uint2*>(k8 + ((g ? npB : npA) & ~3u) + sub * 8);
        float nsA = h2f_(scoresb[((npA & ~3u) >> 2) + lane]);
        float nsB = h2f_(scoresb[((npB & ~3u) >> 2) + lane]);

        float a = dot8(kv);
        #pragma unroll
        for (int o = 1; o < 32; o <<= 1) a += __shfl_xor(a, o);
        float other = __shfl_xor(a, 32);
        float aA = (g ? other : a) + qsel(pkA);
        float aB = (g ? a : other) + qsel(pkB);
        if (i + 1 >= end) aB = -INFINITY;     // odd tail

        float nm = fmaxf(m, fmaxf(aA, aB));
        float c_ = exp2f(m - nm);             // first iter: exp2(-inf)=0
        float w0 = exp2f(aA - nm);
        float w1 = exp2f(aB - nm);
        s = s * c_ + w0 + w1;
        acc = fmaf(acc, c_, fmaf(w0, scA, w1 * scB));
        m = nm;

        pkA = npA; pkB = npB; kv = nkv; scA = nsA; scB = nsB;
    }
    out[(size_t)d * CC + lane] = acc / s;
}

extern "C" void kernel_launch(void* const* d_in, const int* in_sizes, int n_in,
                              void* d_out, int out_size, void* d_ws, size_t ws_size,
                              hipStream_t stream) {
    const float* embedding = (const float*)d_in[0];
    const float* scores    = (const float*)d_in[1];
    const int*   src       = (const int*)d_in[2];
    const int*   dst       = (const int*)d_in[3];
    const int*   typ       = (const int*)d_in[4];
    const float* W1  = (const float*)d_in[5];
    const float* b1  = (const float*)d_in[6];
    const float* W2  = (const float*)d_in[7];
    const float* b2  = (const float*)d_in[8];
    const float* ln_g = (const float*)d_in[9];
    const float* ln_b = (const float*)d_in[10];
    const float* Wl  = (const float*)d_in[11];
    const float* bl  = (const float*)d_in[12];
    const float* Wr  = (const float*)d_in[13];
    const float* br  = (const float*)d_in[14];
    const float* We  = (const float*)d_in[15];
    const float* be  = (const float*)d_in[16];
    const float* emb_table = (const float*)d_in[17];
    float* out = (float*)d_out;
    (void)in_sizes; (void)n_in; (void)out_size; (void)ws_size;

    // ---- workspace carve-up (256-aligned chunks) ----
    char* w = (char*)d_ws;
    auto take = [&](size_t bytes) {
        char* p = w;
        w += (bytes + 255) & ~(size_t)255;
        return p;
    };
    unsigned short* embA = (unsigned short*)take((size_t)NPAD * HH * 2);
    unsigned short* hpre = (unsigned short*)take((size_t)NPAD * HH * 2);
    // BIG buffer: Gch [NPAD][1024] f16 during the MLP; afterwards its first
    // NPAD*512B serve as qbuf [NPAD][256] f16 and the next NPAD*256B as the
    // fp8 k-buffer (Gch dead once GEMM2 reads it).
    unsigned short* Gch  = (unsigned short*)take((size_t)NPAD * 1024 * 2);
    unsigned short* qbuf = Gch;
    unsigned char*  k8   = (unsigned char*)(Gch + (size_t)NPAD * 256);
    unsigned short* W1T  = (unsigned short*)take((size_t)4 * HH * HH * 2);
    unsigned short* W2T  = (unsigned short*)take((size_t)HH * 4 * HH * 2);
    unsigned short* WlrT = (unsigned short*)take((size_t)512 * HH * 2);
    unsigned short* k2t  = (unsigned short*)take(2048);
    unsigned short* scoresb = (unsigned short*)take((size_t)NN * CC * 2);
    float*          uvec = (float*)take(512 * 4);
    float*          vvec = (float*)take(512 * 4);
    int*            cnt  = (int*)take((size_t)NPAD * 4);
    float*          st1  = (float*)take((size_t)NPAD * 4);
    float*          st2  = (float*)take((size_t)NPAD * 4);
    int*            offb = (int*)take((size_t)(NN + 1) * 4);
    int*            cur  = (int*)take((size_t)NN * 4);
    int*            bsum = (int*)take(256 * 4);
    unsigned int*   pack = (unsigned int*)take((size_t)EE * 4 + 64);

    hipMemsetAsync(cnt, 0, (size_t)3 * NPAD * 4, stream);

    // ---- one prep launch ----
    prep_kernel<<<PB7, 256, 0, stream>>>(
        embedding, scores, W1, W2, Wl, Wr, ln_g, ln_b, bl, br, We, be, emb_table,
        embA, scoresb, W1T, W2T, WlrT, k2t, uvec, vvec);

    // ---- CSR build ----
    hist_kernel<<<(EE + 255) / 256, 256, 0, stream>>>(dst, cnt);
    scan_part<<<NB, 256, 0, stream>>>(cnt, offb, bsum);
    scan_sums<<<1, 256, 0, stream>>>(bsum);
    scan_add<<<NB, 256, 0, stream>>>(offb, bsum, cur);
    fill_kernel<<<(EE + 255) / 256, 256, 0, stream>>>(src, dst, typ, cur, pack);

    // ---- MLP (full-grid): hpre = gelu(X@W1+b1)@W2+b2, stats fused ----
    dim3 g1(4 * HH / 128, NPAD / 128);
    mfma_gemm<1, 1, false, false><<<g1, 256, 0, stream>>>(
        embA, W1T, b1, Gch, nullptr, NN, HH, 4 * HH,
        nullptr, nullptr, nullptr, nullptr, nullptr);
    dim3 g2(HH / 128, NPAD / 128);
    mfma_gemm<0, 1, true, false><<<g2, 256, 0, stream>>>(
        Gch, W2T, b2, hpre, nullptr, NN, 4 * HH, HH,
        st1, st2, nullptr, nullptr, nullptr);

    // ---- q|k1 projection with fused LayerNorm; q->f16, k1->fp8 ----
    dim3 gq(512 / 128, NPAD / 128);
    mfma_gemm<0, 2, false, true><<<gq, 256, 0, stream>>>(
        hpre, WlrT, vvec, qbuf, k8, NN, HH, 512,
        nullptr, nullptr, st1, st2, uvec);

    // ---- fused edge phase (fp8 k gathers) ----
    fused_edge_kernel<<<(NN + 3) / 4, 256, 0, stream>>>(
        qbuf, k8, k2t, offb, pack, scoresb, out);
}

// Round 14
// 371.726 us; speedup vs baseline: 1.0505x; 1.0350x over previous
//
#include <hip/hip_runtime.h>
#include <math.h>

#define NN 50000
#define EE 800000
#define HH 256
#define CC 64
#define NPAD 50048          // NN rounded to 128
#define NB 196              // scan blocks = ceil(NN/256)
#define QSCALE 0.09016843798f   // (1/16) * log2(e): folds 1/sqrt(H) and exp->exp2

typedef _Float16 f16x8 __attribute__((ext_vector_type(8)));
typedef _Float16 h2 __attribute__((ext_vector_type(2)));
typedef float f32x4 __attribute__((ext_vector_type(4)));
typedef float f32x2 __attribute__((ext_vector_type(2)));

// exact tanh-gelu via sigmoid identity: 0.5x(1+tanh(z)) = x / (1 + exp(-2z))
__device__ __forceinline__ float gelu_f(float x) {
    const float A = 2.302118074f;    // 2*log2(e)*sqrt(2/pi)
    const float B = 0.1029439565f;   // A*0.044715
    float u = x * fmaf(B, x * x, A);
    float den = 1.0f + exp2f(-u);
#if __has_builtin(__builtin_amdgcn_rcpf)
    return x * __builtin_amdgcn_rcpf(den);
#else
    return x / den;
#endif
}

__device__ __forceinline__ unsigned short f2h(float x) {
    _Float16 h = (_Float16)x;
    return __builtin_bit_cast(unsigned short, h);
}

__device__ __forceinline__ float h2f_(unsigned short u) {
    return (float)__builtin_bit_cast(_Float16, u);
}

__device__ __forceinline__ h2 u2h2(unsigned int u) {
    return __builtin_bit_cast(h2, u);
}

// float -> OCP fp8 e4m3fn (RNE via f16; flush |x|<2^-6 to 0; clamp to 448)
__device__ __forceinline__ unsigned char f2fp8(float v) {
    unsigned short h = f2h(v);
    unsigned s = (h >> 8) & 0x80u;
    int E = (h >> 10) & 31;
    unsigned M = h & 1023u;
    if (E <= 8) return (unsigned char)s;          // tiny -> signed zero
    unsigned m3 = M >> 7, rem = M & 127u;
    m3 += (rem > 64u) || (rem == 64u && (m3 & 1u));
    if (m3 == 8u) { m3 = 0u; ++E; }
    if (E > 23) { E = 23; m3 = 6u; }              // clamp to 448
    if (E == 23 && m3 == 7u) m3 = 6u;             // avoid NaN encoding
    return (unsigned char)(s | ((unsigned)(E - 8) << 3) | m3);
}

// 4x fp8 e4m3 (packed in u32) -> 4x f32 (scalar fallback only)
__device__ __forceinline__ void fp8x4_to_f32(unsigned w, float* o) {
    #pragma unroll
    for (int i = 0; i < 4; ++i) {
        unsigned u8 = (w >> (8 * i)) & 255u;
        unsigned short hb = (u8 & 0x7Fu)
            ? (unsigned short)(((u8 & 0x80u) << 8) | (((u8 & 0x7Fu) << 7) + 0x2000u))
            : (unsigned short)(u8 << 8);
        o[i] = h2f_(hb);
    }
}

__device__ __forceinline__ void gld_lds16(const void* g, void* l) {
    __builtin_amdgcn_global_load_lds(
        (const __attribute__((address_space(1))) unsigned int*)g,
        (__attribute__((address_space(3))) unsigned int*)l,
        16, 0, 0);
}

// ---------------------------------------------------------------------------
// C[M,Nc] = act(A_f16[M,K] @ BT_f16[Nc,K]^T + bias); 128x128 tile, 4 waves,
// 16x16x32 f16 MFMA. BK=32 DOUBLE-BUFFERED in 32KB LDS (same footprint as the
// old single-buffer BK=64 -> occupancy preserved at ~5 blocks/CU): stage(next)
// is issued BEFORE compute(cur), one barrier per K-step, so the
// global_load_lds drain overlaps the 16-MFMA compute phase (T3 minimum).
// Slot rotation swizzle: global chunk g of row r stored at slot (g+(r>>1))&3
// -> ds_read_b128 lands at the free 2-way bank level.
// OUTMODE: 0 = f32 C, 1 = f16 C, 2 = split (col<256 -> f16 q stride 256;
//          col>=256 -> fp8 e4m3 into kout stride 256).
// STATS:  per-row sum/sumsq atomics into st1/st2.
// LNFOLD: out = inv*raw - inv*mu*u[col] + bias[col], mu/inv from rs1/rs2.
// ---------------------------------------------------------------------------
template<int ACT, int OUTMODE, bool STATS, bool LNFOLD>
__global__ __launch_bounds__(256) void mfma_gemm(
    const unsigned short* __restrict__ A,
    const unsigned short* __restrict__ BT,
    const float* __restrict__ bias,
    void* __restrict__ C,
    unsigned char* __restrict__ kout,
    int M, int K, int Nc,
    float* __restrict__ st1, float* __restrict__ st2,
    const float* __restrict__ rs1, const float* __restrict__ rs2,
    const float* __restrict__ uvec)
{
    __shared__ __align__(16) unsigned char lds[32768]; // 2 bufs x (A 8K | B 8K)
    const int t    = threadIdx.x;
    const int lane = t & 63;
    const int wv   = t >> 6;
    const int wr   = wv >> 1, wc = wv & 1;
    const int l16  = lane & 15;
    const int l4   = lane >> 4;
    const int row0 = blockIdx.y * 128;
    const int col0 = blockIdx.x * 128;

    f32x4 acc[4][4] = {};

    // staging: thread t covers rows {srow32, 64+srow32}, slot sslot (16B)
    const int srow32 = t >> 2;               // 0..63
    const int sslot  = t & 3;
    const int gchunk = (sslot - ((srow32 >> 1) & 3)) & 3;  // global chunk at this slot

    const unsigned short* Ab = A  + (size_t)row0 * K;
    const unsigned short* Bb = BT + (size_t)col0 * K;

    auto stage = [&](int p, int k0) {
        #pragma unroll
        for (int i = 0; i < 2; ++i)
            gld_lds16(Ab + (size_t)(i * 64 + srow32) * K + k0 + gchunk * 8,
                      &lds[p * 16384 + i * 4096 + t * 16]);
        #pragma unroll
        for (int i = 0; i < 2; ++i)
            gld_lds16(Bb + (size_t)(i * 64 + srow32) * K + k0 + gchunk * 8,
                      &lds[p * 16384 + 8192 + i * 4096 + t * 16]);
    };

    stage(0, 0);
    __syncthreads();                         // drain prologue stage
    int p = 0;
    for (int k0 = 0; k0 < K; k0 += 32) {
        if (k0 + 32 < K) stage(p ^ 1, k0 + 32);   // prefetch next K-step

        f16x8 af[4], bf[4];
        #pragma unroll
        for (int m = 0; m < 4; ++m) {
            int r = wr * 64 + m * 16 + l16;
            int slot = (l4 + (r >> 1)) & 3;
            af[m] = *reinterpret_cast<const f16x8*>(&lds[p * 16384 + r * 64 + slot * 16]);
        }
        #pragma unroll
        for (int n = 0; n < 4; ++n) {
            int r = wc * 64 + n * 16 + l16;
            int slot = (l4 + (r >> 1)) & 3;
            bf[n] = *reinterpret_cast<const f16x8*>(&lds[p * 16384 + 8192 + r * 64 + slot * 16]);
        }
        #pragma unroll
        for (int m = 0; m < 4; ++m)
            #pragma unroll
            for (int n = 0; n < 4; ++n)
                acc[m][n] = __builtin_amdgcn_mfma_f32_16x16x32_f16(
                    af[m], bf[n], acc[m][n], 0, 0, 0);

        __syncthreads();   // next stage landed (overlapped with MFMAs above)
        p ^= 1;
    }

    float bv[4], uv_[4];
    #pragma unroll
    for (int n = 0; n < 4; ++n) {
        int col = col0 + wc * 64 + n * 16 + l16;
        bv[n] = bias[col];
        if (LNFOLD) uv_[n] = uvec[col];
    }

    #pragma unroll
    for (int m = 0; m < 4; ++m) {
        #pragma unroll
        for (int rg = 0; rg < 4; ++rg) {
            int row = row0 + wr * 64 + m * 16 + l4 * 4 + rg;
            float inv = 0.f, nmu = 0.f;
            if (LNFOLD) {
                float S1 = rs1[row], S2 = rs2[row];
                float mu = S1 * (1.0f / HH);
                float var = S2 * (1.0f / HH) - mu * mu;
                inv = rsqrtf(var + 1e-5f);
                nmu = inv * mu;
            }
            float s1l = 0.f, s2l = 0.f;
            #pragma unroll
            for (int n = 0; n < 4; ++n) {
                float v;
                if (LNFOLD) v = fmaf(inv, acc[m][n][rg], fmaf(-nmu, uv_[n], bv[n]));
                else        v = acc[m][n][rg] + bv[n];
                if (ACT) v = gelu_f(v);
                if (STATS) { s1l += v; s2l += v * v; }
                if (row < M) {
                    int col = col0 + wc * 64 + n * 16 + l16;
                    if (OUTMODE == 0)
                        ((float*)C)[(size_t)row * Nc + col] = v;
                    else if (OUTMODE == 1)
                        ((unsigned short*)C)[(size_t)row * Nc + col] = f2h(v);
                    else {
                        if (col < 256)
                            ((unsigned short*)C)[(size_t)row * 256 + col] = f2h(v);
                        else
                            kout[(size_t)row * 256 + (col - 256)] = f2fp8(v);
                    }
                }
            }
            if (STATS) {
                #pragma unroll
                for (int o = 1; o < 16; o <<= 1) {
                    s1l += __shfl_xor(s1l, o);
                    s2l += __shfl_xor(s2l, o);
                }
                if (l16 == 0 && row < M) {
                    atomicAdd(&st1[row], s1l);
                    atomicAdd(&st2[row], s2l);
                }
            }
        }
    }
}

// ---------------------------------------------------------------------------
// prep mega-kernel: f2h(embedding), f2h(scores), W1T, W2T, WlrT (g-folded,
// q-half scaled by QSCALE), k2 table, u/v fold vectors, AND the CSR histogram
// — one launch.
// ---------------------------------------------------------------------------
#define PB0 12500
#define PB1 (PB0 + 3125)
#define PB2 (PB1 + 1024)
#define PB3 (PB2 + 1024)
#define PB4 (PB3 + 256)
#define PB5 (PB4 + 256)
#define PB6 (PB5 + 3)
#define PB7 (PB6 + 2)
#define PB8 (PB7 + 3125)          // dst histogram
__global__ __launch_bounds__(256) void prep_kernel(
    const float* __restrict__ embedding, const float* __restrict__ scores,
    const float* __restrict__ W1, const float* __restrict__ W2,
    const float* __restrict__ Wl, const float* __restrict__ Wr,
    const float* __restrict__ ln_g, const float* __restrict__ ln_b,
    const float* __restrict__ bl, const float* __restrict__ br,
    const float* __restrict__ We, const float* __restrict__ be,
    const float* __restrict__ emb_table, const int* __restrict__ dst,
    unsigned short* __restrict__ embA, unsigned short* __restrict__ scoresb,
    unsigned short* __restrict__ W1T, unsigned short* __restrict__ W2T,
    unsigned short* __restrict__ WlrT, unsigned short* __restrict__ k2t,
    float* __restrict__ uvec, float* __restrict__ vvec, int* __restrict__ cnt)
{
    const int gb = blockIdx.x, t = threadIdx.x;
    if (gb < PB0) {
        int i = gb * 256 + t;
        float4 v = reinterpret_cast<const float4*>(embedding)[i];
        ushort4 o; o.x = f2h(v.x); o.y = f2h(v.y); o.z = f2h(v.z); o.w = f2h(v.w);
        reinterpret_cast<ushort4*>(embA)[i] = o;
    } else if (gb < PB1) {
        int i = (gb - PB0) * 256 + t;
        float4 v = reinterpret_cast<const float4*>(scores)[i];
        ushort4 o; o.x = f2h(v.x); o.y = f2h(v.y); o.z = f2h(v.z); o.w = f2h(v.w);
        reinterpret_cast<ushort4*>(scoresb)[i] = o;
    } else if (gb < PB2) {
        int o = (gb - PB1) * 256 + t;
        int c = o >> 8, r = o & 255;
        W1T[o] = f2h(W1[r * 1024 + c]);
    } else if (gb < PB3) {
        int o = (gb - PB2) * 256 + t;
        int c = o >> 10, r = o & 1023;
        W2T[o] = f2h(W2[r * 256 + c]);
    } else if (gb < PB4) {
        int o = (gb - PB3) * 256 + t;
        int c = o >> 8, r = o & 255;
        WlrT[o] = f2h(Wl[r * 256 + c] * ln_g[r] * QSCALE);
    } else if (gb < PB5) {
        int o = (gb - PB4) * 256 + t;
        int c = o >> 8, r = o & 255;
        WlrT[65536 + o] = f2h(Wr[r * 256 + c] * ln_g[r]);
    } else if (gb < PB6) {
        int ty = gb - PB5;
        float a = be[t];
        #pragma unroll
        for (int f = 0; f < 20; ++f)
            a += gelu_f(emb_table[ty * 20 + f]) * We[f * 256 + t];
        k2t[ty * 256 + t] = f2h(a);
    } else if (gb < PB7) {
        int c = (gb - PB6) * 256 + t;
        int cc = c & 255;
        const float* W = (c < 256) ? Wl : Wr;
        float u = 0.f, v = 0.f;
        for (int j = 0; j < 256; ++j) {
            float w = W[j * 256 + cc];
            u += ln_g[j] * w;
            v += ln_b[j] * w;
        }
        float sc = (c < 256) ? QSCALE : 1.0f;
        uvec[c] = u * sc;
        vvec[c] = (v + ((c < 256) ? bl[cc] : br[cc])) * sc;
    } else {
        int e = (gb - PB7) * 256 + t;
        if (e < EE) atomicAdd(&cnt[dst[e]], 1);
    }
}

// ---- CSR build ----
__global__ __launch_bounds__(256) void scan_part(
    const int* __restrict__ cnt, int* __restrict__ off, int* __restrict__ bsum)
{
    int b = blockIdx.x, t = threadIdx.x;
    int idx = b * 256 + t;
    int v = (idx < NN) ? cnt[idx] : 0;
    int inc = v;
    #pragma unroll
    for (int o = 1; o < 64; o <<= 1) {
        int u = __shfl_up(inc, o);
        if ((t & 63) >= o) inc += u;
    }
    __shared__ int wt[4];
    if ((t & 63) == 63) wt[t >> 6] = inc;
    __syncthreads();
    int wo = 0;
    #pragma unroll
    for (int w = 0; w < 4; ++w) if (w < (t >> 6)) wo += wt[w];
    if (idx < NN) off[idx] = wo + inc - v;
    if (t == 255) bsum[b] = wo + inc;
}

__global__ __launch_bounds__(256) void scan_sums(int* __restrict__ bsum)
{
    int t = threadIdx.x;
    int v = (t < NB) ? bsum[t] : 0;
    int inc = v;
    #pragma unroll
    for (int o = 1; o < 64; o <<= 1) {
        int u = __shfl_up(inc, o);
        if ((t & 63) >= o) inc += u;
    }
    __shared__ int wt[4];
    if ((t & 63) == 63) wt[t >> 6] = inc;
    __syncthreads();
    int wo = 0;
    #pragma unroll
    for (int w = 0; w < 4; ++w) if (w < (t >> 6)) wo += wt[w];
    if (t < NB) bsum[t] = wo + inc - v;
}

__global__ void scan_add(int* __restrict__ off, const int* __restrict__ bsum,
                         int* __restrict__ cur)
{
    int b = blockIdx.x, t = threadIdx.x;
    int idx = b * 256 + t;
    if (idx < NN) {
        int o = off[idx] + bsum[b];
        off[idx] = o;
        cur[idx] = o;
    }
    if (idx == 0) off[NN] = EE;
}

// pack entry = (src << 8) | ty  -> byte offset of the fp8 k-row, type in low bits
__global__ void fill_kernel(const int* __restrict__ src, const int* __restrict__ dst,
                            const int* __restrict__ typ, int* __restrict__ cur,
                            unsigned int* __restrict__ pack)
{
    int e = blockIdx.x * 256 + threadIdx.x;
    if (e < 16) pack[EE + e] = 0;
    if (e >= EE) return;
    int pos = atomicAdd(&cur[dst[e]], 1);
    pack[pos] = ((unsigned int)src[e] << 8) | (unsigned int)typ[e];
}

// ---------------------------------------------------------------------------
// fused per-dst attention (R11 structure; fp8 k gathers; packed-f32 dot):
// one wave per node; 2 edges in flight, shared 32-lane dot/reduce,
// exp2-domain online softmax, qe prologue, depth-1 prefetch.
// ---------------------------------------------------------------------------
__global__ __launch_bounds__(256) void fused_edge_kernel(
    const unsigned short* __restrict__ qbuf,    // f16 [NPAD][256]: q*QSCALE
    const unsigned char* __restrict__ k8,       // fp8 [NPAD][256]: k1 (g-folded)
    const unsigned short* __restrict__ k2t,     // f16 [3][256]
    const int* __restrict__ off, const unsigned int* __restrict__ pack,
    const unsigned short* __restrict__ scoresb, // f16 [NN][64]
    float* __restrict__ out)
{
    const int t = threadIdx.x, lane = t & 63;
    const int sub = lane & 31;
    const int g = lane >> 5;
    const int d = blockIdx.x * 4 + (t >> 6);
    if (d >= NN) return;
    const int beg = off[d], end = off[d + 1];
    if (beg == end) { out[(size_t)d * CC + lane] = 0.f; return; }

    // q slice: 8 f16 at dims [sub*8, sub*8+8) (duplicated across wave halves)
    uint4 qv = *reinterpret_cast<const uint4*>(
        (const char*)qbuf + (size_t)d * 512 + sub * 16);
    h2 q0 = u2h2(qv.x), q1 = u2h2(qv.y), q2 = u2h2(qv.z), q3 = u2h2(qv.w);
    f32x2 qp0 = {(float)q0[0], (float)q0[1]};
    f32x2 qp1 = {(float)q1[0], (float)q1[1]};
    f32x2 qp2 = {(float)q2[0], (float)q2[1]};
    f32x2 qp3 = {(float)q3[0], (float)q3[1]};

    // qe[ty] = q . k2t[ty] (f16 path, k2t exact)
    float qe0, qe1, qe2;
    {
        uint4 k0v = *reinterpret_cast<const uint4*>((const char*)k2t + 0 * 512 + sub * 16);
        uint4 k1v = *reinterpret_cast<const uint4*>((const char*)k2t + 1 * 512 + sub * 16);
        uint4 k2v = *reinterpret_cast<const uint4*>((const char*)k2t + 2 * 512 + sub * 16);
        auto dot16 = [&](uint4 kv) {
            h2 p = q0 * u2h2(kv.x) + q1 * u2h2(kv.y) + q2 * u2h2(kv.z) + q3 * u2h2(kv.w);
            return (float)p[0] + (float)p[1];
        };
        qe0 = dot16(k0v); qe1 = dot16(k1v); qe2 = dot16(k2v);
        #pragma unroll
        for (int o = 1; o < 32; o <<= 1) {
            qe0 += __shfl_xor(qe0, o);
            qe1 += __shfl_xor(qe1, o);
            qe2 += __shfl_xor(qe2, o);
        }
    }
    auto qsel = [&](unsigned pk) {
        int ty = pk & 3;
        return (ty == 0) ? qe0 : (ty == 1) ? qe1 : qe2;
    };
    auto dot8 = [&](uint2 kv) {
#if __has_builtin(__builtin_amdgcn_cvt_pk_f32_fp8)
        auto k0 = __builtin_amdgcn_cvt_pk_f32_fp8(kv.x, false);
        auto k1 = __builtin_amdgcn_cvt_pk_f32_fp8(kv.x, true);
        auto k2 = __builtin_amdgcn_cvt_pk_f32_fp8(kv.y, false);
        auto k3 = __builtin_amdgcn_cvt_pk_f32_fp8(kv.y, true);
        f32x2 s01 = qp0 * f32x2{k0[0], k0[1]} + qp1 * f32x2{k1[0], k1[1]};
        f32x2 s23 = qp2 * f32x2{k2[0], k2[1]} + qp3 * f32x2{k3[0], k3[1]};
        f32x2 s = s01 + s23;
        return s[0] + s[1];
#else
        float kf[8];
        fp8x4_to_f32(kv.x, kf);
        fp8x4_to_f32(kv.y, kf + 4);
        float u0 = fmaf(qp0[1], kf[1], qp0[0] * kf[0]);
        float u1 = fmaf(qp1[1], kf[3], qp1[0] * kf[2]);
        float u2 = fmaf(qp2[1], kf[5], qp2[0] * kf[4]);
        float u3 = fmaf(qp3[1], kf[7], qp3[0] * kf[6]);
        return (u0 + u1) + (u2 + u3);
#endif
    };

    // prologue: pair {beg, beg+1}
    unsigned pkA = pack[beg], pkB = pack[beg + 1];
    uint2 kv = *reinterpret_cast<const uint2*>(k8 + ((g ? pkB : pkA) & ~3u) + sub * 8);
    float scA = h2f_(scoresb[((pkA & ~3u) >> 2) + lane]);
    float scB = h2f_(scoresb[((pkB & ~3u) >> 2) + lane]);

    float m = -INFINITY, s = 0.f, acc = 0.f;

    for (int i = beg; i < end; i += 2) {
        int inext = (i + 2 < end) ? i + 2 : i;
        unsigned npA = pack[inext], npB = pack[inext + 1];
        uint2 nkv = *reinterpret_cast<const uint2*>(k8 + ((g ? npB : npA) & ~3u) + sub * 8);
        float nsA = h2f_(scoresb[((npA & ~3u) >> 2) + lane]);
        float nsB = h2f_(scoresb[((npB & ~3u) >> 2) + lane]);

        float a = dot8(kv);
        #pragma unroll
        for (int o = 1; o < 32; o <<= 1) a += __shfl_xor(a, o);
        float other = __shfl_xor(a, 32);
        float aA = (g ? other : a) + qsel(pkA);
        float aB = (g ? a : other) + qsel(pkB);
        if (i + 1 >= end) aB = -INFINITY;     // odd tail

        float nm = fmaxf(m, fmaxf(aA, aB));
        float c_ = exp2f(m - nm);             // first iter: exp2(-inf)=0
        float w0 = exp2f(aA - nm);
        float w1 = exp2f(aB - nm);
        s = s * c_ + w0 + w1;
        acc = fmaf(acc, c_, fmaf(w0, scA, w1 * scB));
        m = nm;

        pkA = npA; pkB = npB; kv = nkv; scA = nsA; scB = nsB;
    }
    out[(size_t)d * CC + lane] = acc / s;
}

extern "C" void kernel_launch(void* const* d_in, const int* in_sizes, int n_in,
                              void* d_out, int out_size, void* d_ws, size_t ws_size,
                              hipStream_t stream) {
    const float* embedding = (const float*)d_in[0];
    const float* scores    = (const float*)d_in[1];
    const int*   src       = (const int*)d_in[2];
    const int*   dst       = (const int*)d_in[3];
    const int*   typ       = (const int*)d_in[4];
    const float* W1  = (const float*)d_in[5];
    const float* b1  = (const float*)d_in[6];
    const float* W2  = (const float*)d_in[7];
    const float* b2  = (const float*)d_in[8];
    const float* ln_g = (const float*)d_in[9];
    const float* ln_b = (const float*)d_in[10];
    const float* Wl  = (const float*)d_in[11];
    const float* bl  = (const float*)d_in[12];
    const float* Wr  = (const float*)d_in[13];
    const float* br  = (const float*)d_in[14];
    const float* We  = (const float*)d_in[15];
    const float* be  = (const float*)d_in[16];
    const float* emb_table = (const float*)d_in[17];
    float* out = (float*)d_out;
    (void)in_sizes; (void)n_in; (void)out_size; (void)ws_size;

    // ---- workspace carve-up (256-aligned chunks) ----
    char* w = (char*)d_ws;
    auto take = [&](size_t bytes) {
        char* p = w;
        w += (bytes + 255) & ~(size_t)255;
        return p;
    };
    unsigned short* embA = (unsigned short*)take((size_t)NPAD * HH * 2);
    unsigned short* hpre = (unsigned short*)take((size_t)NPAD * HH * 2);
    // BIG buffer: Gch [NPAD][1024] f16 during the MLP; afterwards its first
    // NPAD*512B serve as qbuf [NPAD][256] f16 and the next NPAD*256B as the
    // fp8 k-buffer (Gch dead once GEMM2 reads it).
    unsigned short* Gch  = (unsigned short*)take((size_t)NPAD * 1024 * 2);
    unsigned short* qbuf = Gch;
    unsigned char*  k8   = (unsigned char*)(Gch + (size_t)NPAD * 256);
    unsigned short* W1T  = (unsigned short*)take((size_t)4 * HH * HH * 2);
    unsigned short* W2T  = (unsigned short*)take((size_t)HH * 4 * HH * 2);
    unsigned short* WlrT = (unsigned short*)take((size_t)512 * HH * 2);
    unsigned short* k2t  = (unsigned short*)take(2048);
    unsigned short* scoresb = (unsigned short*)take((size_t)NN * CC * 2);
    float*          uvec = (float*)take(512 * 4);
    float*          vvec = (float*)take(512 * 4);
    int*            cnt  = (int*)take((size_t)NPAD * 4);
    float*          st1  = (float*)take((size_t)NPAD * 4);
    float*          st2  = (float*)take((size_t)NPAD * 4);
    int*            offb = (int*)take((size_t)(NN + 1) * 4);
    int*            cur  = (int*)take((size_t)NN * 4);
    int*            bsum = (int*)take(256 * 4);
    unsigned int*   pack = (unsigned int*)take((size_t)EE * 4 + 64);

    hipMemsetAsync(cnt, 0, (size_t)3 * NPAD * 4, stream);

    // ---- one prep launch (conversions + transposes + k2 + u/v + histogram) ----
    prep_kernel<<<PB8, 256, 0, stream>>>(
        embedding, scores, W1, W2, Wl, Wr, ln_g, ln_b, bl, br, We, be,
        emb_table, dst,
        embA, scoresb, W1T, W2T, WlrT, k2t, uvec, vvec, cnt);

    // ---- CSR build ----
    scan_part<<<NB, 256, 0, stream>>>(cnt, offb, bsum);
    scan_sums<<<1, 256, 0, stream>>>(bsum);
    scan_add<<<NB, 256, 0, stream>>>(offb, bsum, cur);
    fill_kernel<<<(EE + 255) / 256, 256, 0, stream>>>(src, dst, typ, cur, pack);

    // ---- MLP (full-grid): hpre = gelu(X@W1+b1)@W2+b2, stats fused ----
    dim3 g1(4 * HH / 128, NPAD / 128);
    mfma_gemm<1, 1, false, false><<<g1, 256, 0, stream>>>(
        embA, W1T, b1, Gch, nullptr, NN, HH, 4 * HH,
        nullptr, nullptr, nullptr, nullptr, nullptr);
    dim3 g2(HH / 128, NPAD / 128);
    mfma_gemm<0, 1, true, false><<<g2, 256, 0, stream>>>(
        Gch, W2T, b2, hpre, nullptr, NN, 4 * HH, HH,
        st1, st2, nullptr, nullptr, nullptr);

    // ---- q|k1 projection with fused LayerNorm; q->f16, k1->fp8 ----
    dim3 gq(512 / 128, NPAD / 128);
    mfma_gemm<0, 2, false, true><<<gq, 256, 0, stream>>>(
        hpre, WlrT, vvec, qbuf, k8, NN, HH, 512,
        nullptr, nullptr, st1, st2, uvec);

    // ---- fused edge phase (fp8 k gathers) ----
    fused_edge_kernel<<<(NN + 3) / 4, 256, 0, stream>>>(
        qbuf, k8, k2t, offb, pack, scoresb, out);
}

// Round 15
// 357.794 us; speedup vs baseline: 1.0914x; 1.0389x over previous
//
#include <hip/hip_runtime.h>
#include <math.h>

#define NN 50000
#define EE 800000
#define HH 256
#define CC 64
#define NPAD 50048          // NN rounded to 128
#define NB 196              // scan blocks = ceil(NN/256)
#define QSCALE 0.09016843798f   // (1/16) * log2(e): folds 1/sqrt(H) and exp->exp2

typedef _Float16 f16x8 __attribute__((ext_vector_type(8)));
typedef _Float16 h2 __attribute__((ext_vector_type(2)));
typedef float f32x4 __attribute__((ext_vector_type(4)));
typedef float f32x2 __attribute__((ext_vector_type(2)));

// exact tanh-gelu via sigmoid identity: 0.5x(1+tanh(z)) = x / (1 + exp(-2z))
__device__ __forceinline__ float gelu_f(float x) {
    const float A = 2.302118074f;    // 2*log2(e)*sqrt(2/pi)
    const float B = 0.1029439565f;   // A*0.044715
    float u = x * fmaf(B, x * x, A);
    float den = 1.0f + exp2f(-u);
#if __has_builtin(__builtin_amdgcn_rcpf)
    return x * __builtin_amdgcn_rcpf(den);
#else
    return x / den;
#endif
}

__device__ __forceinline__ unsigned short f2h(float x) {
    _Float16 h = (_Float16)x;
    return __builtin_bit_cast(unsigned short, h);
}

__device__ __forceinline__ float h2f_(unsigned short u) {
    return (float)__builtin_bit_cast(_Float16, u);
}

__device__ __forceinline__ h2 u2h2(unsigned int u) {
    return __builtin_bit_cast(h2, u);
}

// float -> OCP fp8 e4m3fn (RNE via f16; flush |x|<2^-6 to 0; clamp to 448)
__device__ __forceinline__ unsigned char f2fp8(float v) {
    unsigned short h = f2h(v);
    unsigned s = (h >> 8) & 0x80u;
    int E = (h >> 10) & 31;
    unsigned M = h & 1023u;
    if (E <= 8) return (unsigned char)s;          // tiny -> signed zero
    unsigned m3 = M >> 7, rem = M & 127u;
    m3 += (rem > 64u) || (rem == 64u && (m3 & 1u));
    if (m3 == 8u) { m3 = 0u; ++E; }
    if (E > 23) { E = 23; m3 = 6u; }              // clamp to 448
    if (E == 23 && m3 == 7u) m3 = 6u;             // avoid NaN encoding
    return (unsigned char)(s | ((unsigned)(E - 8) << 3) | m3);
}

// 4x fp8 e4m3 (packed in u32) -> 4x f32 (scalar fallback only)
__device__ __forceinline__ void fp8x4_to_f32(unsigned w, float* o) {
    #pragma unroll
    for (int i = 0; i < 4; ++i) {
        unsigned u8 = (w >> (8 * i)) & 255u;
        unsigned short hb = (u8 & 0x7Fu)
            ? (unsigned short)(((u8 & 0x80u) << 8) | (((u8 & 0x7Fu) << 7) + 0x2000u))
            : (unsigned short)(u8 << 8);
        o[i] = h2f_(hb);
    }
}

__device__ __forceinline__ void gld_lds16(const void* g, void* l) {
    __builtin_amdgcn_global_load_lds(
        (const __attribute__((address_space(1))) unsigned int*)g,
        (__attribute__((address_space(3))) unsigned int*)l,
        16, 0, 0);
}

// T1: bijective XCD-aware remap (m204). HW round-robins consecutive flat ids
// across 8 XCDs; remap so each XCD owns a CONTIGUOUS run of logical tiles ->
// A row-panels become XCD-L2-resident across col-tiles.
__device__ __forceinline__ void xcd_tiles(int& tx, int& ty) {
    int gx = gridDim.x;
    int nwg = gx * gridDim.y;
    int flat = blockIdx.y * gx + blockIdx.x;     // hw dispatch order
    int q = nwg >> 3, r = nwg & 7;
    int xcd = flat & 7, j = flat >> 3;
    int idx = ((xcd < r) ? xcd * (q + 1) : r * (q + 1) + (xcd - r) * q) + j;
    tx = idx % gx;
    ty = idx / gx;
}

// ---------------------------------------------------------------------------
// C[M,Nc] = act(A_f16[M,K] @ BT_f16[Nc,K]^T + bias); 128x128 tile, 4 waves,
// 16x16x32 f16 MFMA. BK=32 double-buffered in 32KB LDS; stage(next) issued
// before compute(cur), one barrier per K-step. Slot-rotation swizzle keeps
// ds_read_b128 at the free 2-way level. XCD-swizzled tile assignment (T1).
// OUTMODE: 0 = f32 C, 1 = f16 C, 2 = split (col<256 -> f16 q stride 256;
//          col>=256 -> fp8 e4m3 into kout stride 256).
// STATS:  per-row sum/sumsq atomics into st1/st2.
// LNFOLD: out = inv*raw - inv*mu*u[col] + bias[col], mu/inv from rs1/rs2.
// ---------------------------------------------------------------------------
template<int ACT, int OUTMODE, bool STATS, bool LNFOLD>
__global__ __launch_bounds__(256) void mfma_gemm(
    const unsigned short* __restrict__ A,
    const unsigned short* __restrict__ BT,
    const float* __restrict__ bias,
    void* __restrict__ C,
    unsigned char* __restrict__ kout,
    int M, int K, int Nc,
    float* __restrict__ st1, float* __restrict__ st2,
    const float* __restrict__ rs1, const float* __restrict__ rs2,
    const float* __restrict__ uvec)
{
    __shared__ __align__(16) unsigned char lds[32768]; // 2 bufs x (A 8K | B 8K)
    const int t    = threadIdx.x;
    const int lane = t & 63;
    const int wv   = t >> 6;
    const int wr   = wv >> 1, wc = wv & 1;
    const int l16  = lane & 15;
    const int l4   = lane >> 4;
    int tx, ty;
    xcd_tiles(tx, ty);
    const int row0 = ty * 128;
    const int col0 = tx * 128;

    f32x4 acc[4][4] = {};

    // staging: thread t covers rows {srow32, 64+srow32}, slot sslot (16B)
    const int srow32 = t >> 2;               // 0..63
    const int sslot  = t & 3;
    const int gchunk = (sslot - ((srow32 >> 1) & 3)) & 3;  // global chunk at this slot

    const unsigned short* Ab = A  + (size_t)row0 * K;
    const unsigned short* Bb = BT + (size_t)col0 * K;

    auto stage = [&](int p, int k0) {
        #pragma unroll
        for (int i = 0; i < 2; ++i)
            gld_lds16(Ab + (size_t)(i * 64 + srow32) * K + k0 + gchunk * 8,
                      &lds[p * 16384 + i * 4096 + t * 16]);
        #pragma unroll
        for (int i = 0; i < 2; ++i)
            gld_lds16(Bb + (size_t)(i * 64 + srow32) * K + k0 + gchunk * 8,
                      &lds[p * 16384 + 8192 + i * 4096 + t * 16]);
    };

    stage(0, 0);
    __syncthreads();                         // drain prologue stage
    int p = 0;
    for (int k0 = 0; k0 < K; k0 += 32) {
        if (k0 + 32 < K) stage(p ^ 1, k0 + 32);   // prefetch next K-step

        f16x8 af[4], bf[4];
        #pragma unroll
        for (int m = 0; m < 4; ++m) {
            int r = wr * 64 + m * 16 + l16;
            int slot = (l4 + (r >> 1)) & 3;
            af[m] = *reinterpret_cast<const f16x8*>(&lds[p * 16384 + r * 64 + slot * 16]);
        }
        #pragma unroll
        for (int n = 0; n < 4; ++n) {
            int r = wc * 64 + n * 16 + l16;
            int slot = (l4 + (r >> 1)) & 3;
            bf[n] = *reinterpret_cast<const f16x8*>(&lds[p * 16384 + 8192 + r * 64 + slot * 16]);
        }
        #pragma unroll
        for (int m = 0; m < 4; ++m)
            #pragma unroll
            for (int n = 0; n < 4; ++n)
                acc[m][n] = __builtin_amdgcn_mfma_f32_16x16x32_f16(
                    af[m], bf[n], acc[m][n], 0, 0, 0);

        __syncthreads();   // next stage landed (overlapped with MFMAs above)
        p ^= 1;
    }

    float bv[4], uv_[4];
    #pragma unroll
    for (int n = 0; n < 4; ++n) {
        int col = col0 + wc * 64 + n * 16 + l16;
        bv[n] = bias[col];
        if (LNFOLD) uv_[n] = uvec[col];
    }

    #pragma unroll
    for (int m = 0; m < 4; ++m) {
        #pragma unroll
        for (int rg = 0; rg < 4; ++rg) {
            int row = row0 + wr * 64 + m * 16 + l4 * 4 + rg;
            float inv = 0.f, nmu = 0.f;
            if (LNFOLD) {
                float S1 = rs1[row], S2 = rs2[row];
                float mu = S1 * (1.0f / HH);
                float var = S2 * (1.0f / HH) - mu * mu;
                inv = rsqrtf(var + 1e-5f);
                nmu = inv * mu;
            }
            float s1l = 0.f, s2l = 0.f;
            #pragma unroll
            for (int n = 0; n < 4; ++n) {
                float v;
                if (LNFOLD) v = fmaf(inv, acc[m][n][rg], fmaf(-nmu, uv_[n], bv[n]));
                else        v = acc[m][n][rg] + bv[n];
                if (ACT) v = gelu_f(v);
                if (STATS) { s1l += v; s2l += v * v; }
                if (row < M) {
                    int col = col0 + wc * 64 + n * 16 + l16;
                    if (OUTMODE == 0)
                        ((float*)C)[(size_t)row * Nc + col] = v;
                    else if (OUTMODE == 1)
                        ((unsigned short*)C)[(size_t)row * Nc + col] = f2h(v);
                    else {
                        if (col < 256)
                            ((unsigned short*)C)[(size_t)row * 256 + col] = f2h(v);
                        else
                            kout[(size_t)row * 256 + (col - 256)] = f2fp8(v);
                    }
                }
            }
            if (STATS) {
                #pragma unroll
                for (int o = 1; o < 16; o <<= 1) {
                    s1l += __shfl_xor(s1l, o);
                    s2l += __shfl_xor(s2l, o);
                }
                if (l16 == 0 && row < M) {
                    atomicAdd(&st1[row], s1l);
                    atomicAdd(&st2[row], s2l);
                }
            }
        }
    }
}

// ---------------------------------------------------------------------------
// prep mega-kernel: f2h(embedding), f2h(scores), W1T, W2T, WlrT (g-folded,
// q-half scaled by QSCALE), k2 table, u/v fold vectors, AND the CSR histogram
// — one launch.
// ---------------------------------------------------------------------------
#define PB0 12500
#define PB1 (PB0 + 3125)
#define PB2 (PB1 + 1024)
#define PB3 (PB2 + 1024)
#define PB4 (PB3 + 256)
#define PB5 (PB4 + 256)
#define PB6 (PB5 + 3)
#define PB7 (PB6 + 2)
#define PB8 (PB7 + 3125)          // dst histogram
__global__ __launch_bounds__(256) void prep_kernel(
    const float* __restrict__ embedding, const float* __restrict__ scores,
    const float* __restrict__ W1, const float* __restrict__ W2,
    const float* __restrict__ Wl, const float* __restrict__ Wr,
    const float* __restrict__ ln_g, const float* __restrict__ ln_b,
    const float* __restrict__ bl, const float* __restrict__ br,
    const float* __restrict__ We, const float* __restrict__ be,
    const float* __restrict__ emb_table, const int* __restrict__ dst,
    unsigned short* __restrict__ embA, unsigned short* __restrict__ scoresb,
    unsigned short* __restrict__ W1T, unsigned short* __restrict__ W2T,
    unsigned short* __restrict__ WlrT, unsigned short* __restrict__ k2t,
    float* __restrict__ uvec, float* __restrict__ vvec, int* __restrict__ cnt)
{
    const int gb = blockIdx.x, t = threadIdx.x;
    if (gb < PB0) {
        int i = gb * 256 + t;
        float4 v = reinterpret_cast<const float4*>(embedding)[i];
        ushort4 o; o.x = f2h(v.x); o.y = f2h(v.y); o.z = f2h(v.z); o.w = f2h(v.w);
        reinterpret_cast<ushort4*>(embA)[i] = o;
    } else if (gb < PB1) {
        int i = (gb - PB0) * 256 + t;
        float4 v = reinterpret_cast<const float4*>(scores)[i];
        ushort4 o; o.x = f2h(v.x); o.y = f2h(v.y); o.z = f2h(v.z); o.w = f2h(v.w);
        reinterpret_cast<ushort4*>(scoresb)[i] = o;
    } else if (gb < PB2) {
        int o = (gb - PB1) * 256 + t;
        int c = o >> 8, r = o & 255;
        W1T[o] = f2h(W1[r * 1024 + c]);
    } else if (gb < PB3) {
        int o = (gb - PB2) * 256 + t;
        int c = o >> 10, r = o & 1023;
        W2T[o] = f2h(W2[r * 256 + c]);
    } else if (gb < PB4) {
        int o = (gb - PB3) * 256 + t;
        int c = o >> 8, r = o & 255;
        WlrT[o] = f2h(Wl[r * 256 + c] * ln_g[r] * QSCALE);
    } else if (gb < PB5) {
        int o = (gb - PB4) * 256 + t;
        int c = o >> 8, r = o & 255;
        WlrT[65536 + o] = f2h(Wr[r * 256 + c] * ln_g[r]);
    } else if (gb < PB6) {
        int ty = gb - PB5;
        float a = be[t];
        #pragma unroll
        for (int f = 0; f < 20; ++f)
            a += gelu_f(emb_table[ty * 20 + f]) * We[f * 256 + t];
        k2t[ty * 256 + t] = f2h(a);
    } else if (gb < PB7) {
        int c = (gb - PB6) * 256 + t;
        int cc = c & 255;
        const float* W = (c < 256) ? Wl : Wr;
        float u = 0.f, v = 0.f;
        for (int j = 0; j < 256; ++j) {
            float w = W[j * 256 + cc];
            u += ln_g[j] * w;
            v += ln_b[j] * w;
        }
        float sc = (c < 256) ? QSCALE : 1.0f;
        uvec[c] = u * sc;
        vvec[c] = (v + ((c < 256) ? bl[cc] : br[cc])) * sc;
    } else {
        int e = (gb - PB7) * 256 + t;
        if (e < EE) atomicAdd(&cnt[dst[e]], 1);
    }
}

// ---- CSR build ----
__global__ __launch_bounds__(256) void scan_part(
    const int* __restrict__ cnt, int* __restrict__ off, int* __restrict__ bsum)
{
    int b = blockIdx.x, t = threadIdx.x;
    int idx = b * 256 + t;
    int v = (idx < NN) ? cnt[idx] : 0;
    int inc = v;
    #pragma unroll
    for (int o = 1; o < 64; o <<= 1) {
        int u = __shfl_up(inc, o);
        if ((t & 63) >= o) inc += u;
    }
    __shared__ int wt[4];
    if ((t & 63) == 63) wt[t >> 6] = inc;
    __syncthreads();
    int wo = 0;
    #pragma unroll
    for (int w = 0; w < 4; ++w) if (w < (t >> 6)) wo += wt[w];
    if (idx < NN) off[idx] = wo + inc - v;
    if (t == 255) bsum[b] = wo + inc;
}

__global__ __launch_bounds__(256) void scan_sums(int* __restrict__ bsum)
{
    int t = threadIdx.x;
    int v = (t < NB) ? bsum[t] : 0;
    int inc = v;
    #pragma unroll
    for (int o = 1; o < 64; o <<= 1) {
        int u = __shfl_up(inc, o);
        if ((t & 63) >= o) inc += u;
    }
    __shared__ int wt[4];
    if ((t & 63) == 63) wt[t >> 6] = inc;
    __syncthreads();
    int wo = 0;
    #pragma unroll
    for (int w = 0; w < 4; ++w) if (w < (t >> 6)) wo += wt[w];
    if (t < NB) bsum[t] = wo + inc - v;
}

__global__ void scan_add(int* __restrict__ off, const int* __restrict__ bsum,
                         int* __restrict__ cur)
{
    int b = blockIdx.x, t = threadIdx.x;
    int idx = b * 256 + t;
    if (idx < NN) {
        int o = off[idx] + bsum[b];
        off[idx] = o;
        cur[idx] = o;
    }
    if (idx == 0) off[NN] = EE;
}

// pack entry = (src << 8) | ty  -> byte offset of the fp8 k-row, type in low bits
__global__ void fill_kernel(const int* __restrict__ src, const int* __restrict__ dst,
                            const int* __restrict__ typ, int* __restrict__ cur,
                            unsigned int* __restrict__ pack)
{
    int e = blockIdx.x * 256 + threadIdx.x;
    if (e < 16) pack[EE + e] = 0;
    if (e >= EE) return;
    int pos = atomicAdd(&cur[dst[e]], 1);
    pack[pos] = ((unsigned int)src[e] << 8) | (unsigned int)typ[e];
}

// ---------------------------------------------------------------------------
// fused per-dst attention (R14 structure + T13 defer-max):
// one wave per node; 2 edges in flight, shared 32-lane dot/reduce, fp8 k
// gathers, exp2-domain online softmax with deferred rescale (wave-uniform
// branch; weights bounded by 2^11.5), qe prologue, depth-1 prefetch.
// ---------------------------------------------------------------------------
__global__ __launch_bounds__(256) void fused_edge_kernel(
    const unsigned short* __restrict__ qbuf,    // f16 [NPAD][256]: q*QSCALE
    const unsigned char* __restrict__ k8,       // fp8 [NPAD][256]: k1 (g-folded)
    const unsigned short* __restrict__ k2t,     // f16 [3][256]
    const int* __restrict__ off, const unsigned int* __restrict__ pack,
    const unsigned short* __restrict__ scoresb, // f16 [NN][64]
    float* __restrict__ out)
{
    const int t = threadIdx.x, lane = t & 63;
    const int sub = lane & 31;
    const int g = lane >> 5;
    const int d = blockIdx.x * 4 + (t >> 6);
    if (d >= NN) return;
    const int beg = off[d], end = off[d + 1];
    if (beg == end) { out[(size_t)d * CC + lane] = 0.f; return; }

    // q slice: 8 f16 at dims [sub*8, sub*8+8) (duplicated across wave halves)
    uint4 qv = *reinterpret_cast<const uint4*>(
        (const char*)qbuf + (size_t)d * 512 + sub * 16);
    h2 q0 = u2h2(qv.x), q1 = u2h2(qv.y), q2 = u2h2(qv.z), q3 = u2h2(qv.w);
    f32x2 qp0 = {(float)q0[0], (float)q0[1]};
    f32x2 qp1 = {(float)q1[0], (float)q1[1]};
    f32x2 qp2 = {(float)q2[0], (float)q2[1]};
    f32x2 qp3 = {(float)q3[0], (float)q3[1]};

    // qe[ty] = q . k2t[ty] (f16 path, k2t exact)
    float qe0, qe1, qe2;
    {
        uint4 k0v = *reinterpret_cast<const uint4*>((const char*)k2t + 0 * 512 + sub * 16);
        uint4 k1v = *reinterpret_cast<const uint4*>((const char*)k2t + 1 * 512 + sub * 16);
        uint4 k2v = *reinterpret_cast<const uint4*>((const char*)k2t + 2 * 512 + sub * 16);
        auto dot16 = [&](uint4 kv) {
            h2 p = q0 * u2h2(kv.x) + q1 * u2h2(kv.y) + q2 * u2h2(kv.z) + q3 * u2h2(kv.w);
            return (float)p[0] + (float)p[1];
        };
        qe0 = dot16(k0v); qe1 = dot16(k1v); qe2 = dot16(k2v);
        #pragma unroll
        for (int o = 1; o < 32; o <<= 1) {
            qe0 += __shfl_xor(qe0, o);
            qe1 += __shfl_xor(qe1, o);
            qe2 += __shfl_xor(qe2, o);
        }
    }
    auto qsel = [&](unsigned pk) {
        int ty = pk & 3;
        return (ty == 0) ? qe0 : (ty == 1) ? qe1 : qe2;
    };
    auto dot8 = [&](uint2 kv) {
#if __has_builtin(__builtin_amdgcn_cvt_pk_f32_fp8)
        auto k0 = __builtin_amdgcn_cvt_pk_f32_fp8(kv.x, false);
        auto k1 = __builtin_amdgcn_cvt_pk_f32_fp8(kv.x, true);
        auto k2 = __builtin_amdgcn_cvt_pk_f32_fp8(kv.y, false);
        auto k3 = __builtin_amdgcn_cvt_pk_f32_fp8(kv.y, true);
        f32x2 s01 = qp0 * f32x2{k0[0], k0[1]} + qp1 * f32x2{k1[0], k1[1]};
        f32x2 s23 = qp2 * f32x2{k2[0], k2[1]} + qp3 * f32x2{k3[0], k3[1]};
        f32x2 s = s01 + s23;
        return s[0] + s[1];
#else
        float kf[8];
        fp8x4_to_f32(kv.x, kf);
        fp8x4_to_f32(kv.y, kf + 4);
        float u0 = fmaf(qp0[1], kf[1], qp0[0] * kf[0]);
        float u1 = fmaf(qp1[1], kf[3], qp1[0] * kf[2]);
        float u2 = fmaf(qp2[1], kf[5], qp2[0] * kf[4]);
        float u3 = fmaf(qp3[1], kf[7], qp3[0] * kf[6]);
        return (u0 + u1) + (u2 + u3);
#endif
    };

    // prologue: pair {beg, beg+1}
    unsigned pkA = pack[beg], pkB = pack[beg + 1];
    uint2 kv = *reinterpret_cast<const uint2*>(k8 + ((g ? pkB : pkA) & ~3u) + sub * 8);
    float scA = h2f_(scoresb[((pkA & ~3u) >> 2) + lane]);
    float scB = h2f_(scoresb[((pkB & ~3u) >> 2) + lane]);

    float m = -INFINITY, s = 0.f, acc = 0.f;

    for (int i = beg; i < end; i += 2) {
        int inext = (i + 2 < end) ? i + 2 : i;
        unsigned npA = pack[inext], npB = pack[inext + 1];
        uint2 nkv = *reinterpret_cast<const uint2*>(k8 + ((g ? npB : npA) & ~3u) + sub * 8);
        float nsA = h2f_(scoresb[((npA & ~3u) >> 2) + lane]);
        float nsB = h2f_(scoresb[((npB & ~3u) >> 2) + lane]);

        float a = dot8(kv);
        #pragma unroll
        for (int o = 1; o < 32; o <<= 1) a += __shfl_xor(a, o);
        float other = __shfl_xor(a, 32);
        float aA = (g ? other : a) + qsel(pkA);
        float aB = (g ? a : other) + qsel(pkB);
        if (i + 1 >= end) aB = -INFINITY;     // odd tail

        // T13 defer-max: rescale only when the running max grows by >11.5
        // (exp2-domain); weights stay bounded by 2^11.5 -- mathematically
        // exact softmax, but the common path has no exp2->fma serial chain.
        float bm = fmaxf(aA, aB);             // wave-uniform
        if (bm > m + 11.5f) {
            float c_ = exp2f(m - bm);         // first iter: exp2(-inf)=0
            s *= c_;
            acc *= c_;
            m = bm;
        }
        float w0 = exp2f(aA - m);
        float w1 = exp2f(aB - m);
        s += w0 + w1;
        acc = fmaf(w0, scA, fmaf(w1, scB, acc));

        pkA = npA; pkB = npB; kv = nkv; scA = nsA; scB = nsB;
    }
    out[(size_t)d * CC + lane] = acc / s;
}

extern "C" void kernel_launch(void* const* d_in, const int* in_sizes, int n_in,
                              void* d_out, int out_size, void* d_ws, size_t ws_size,
                              hipStream_t stream) {
    const float* embedding = (const float*)d_in[0];
    const float* scores    = (const float*)d_in[1];
    const int*   src       = (const int*)d_in[2];
    const int*   dst       = (const int*)d_in[3];
    const int*   typ       = (const int*)d_in[4];
    const float* W1  = (const float*)d_in[5];
    const float* b1  = (const float*)d_in[6];
    const float* W2  = (const float*)d_in[7];
    const float* b2  = (const float*)d_in[8];
    const float* ln_g = (const float*)d_in[9];
    const float* ln_b = (const float*)d_in[10];
    const float* Wl  = (const float*)d_in[11];
    const float* bl  = (const float*)d_in[12];
    const float* Wr  = (const float*)d_in[13];
    const float* br  = (const float*)d_in[14];
    const float* We  = (const float*)d_in[15];
    const float* be  = (const float*)d_in[16];
    const float* emb_table = (const float*)d_in[17];
    float* out = (float*)d_out;
    (void)in_sizes; (void)n_in; (void)out_size; (void)ws_size;

    // ---- workspace carve-up (256-aligned chunks) ----
    char* w = (char*)d_ws;
    auto take = [&](size_t bytes) {
        char* p = w;
        w += (bytes + 255) & ~(size_t)255;
        return p;
    };
    unsigned short* embA = (unsigned short*)take((size_t)NPAD * HH * 2);
    unsigned short* hpre = (unsigned short*)take((size_t)NPAD * HH * 2);
    // BIG buffer: Gch [NPAD][1024] f16 during the MLP; afterwards its first
    // NPAD*512B serve as qbuf [NPAD][256] f16 and the next NPAD*256B as the
    // fp8 k-buffer (Gch dead once GEMM2 reads it).
    unsigned short* Gch  = (unsigned short*)take((size_t)NPAD * 1024 * 2);
    unsigned short* qbuf = Gch;
    unsigned char*  k8   = (unsigned char*)(Gch + (size_t)NPAD * 256);
    unsigned short* W1T  = (unsigned short*)take((size_t)4 * HH * HH * 2);
    unsigned short* W2T  = (unsigned short*)take((size_t)HH * 4 * HH * 2);
    unsigned short* WlrT = (unsigned short*)take((size_t)512 * HH * 2);
    unsigned short* k2t  = (unsigned short*)take(2048);
    unsigned short* scoresb = (unsigned short*)take((size_t)NN * CC * 2);
    float*          uvec = (float*)take(512 * 4);
    float*          vvec = (float*)take(512 * 4);
    int*            cnt  = (int*)take((size_t)NPAD * 4);
    float*          st1  = (float*)take((size_t)NPAD * 4);
    float*          st2  = (float*)take((size_t)NPAD * 4);
    int*            offb = (int*)take((size_t)(NN + 1) * 4);
    int*            cur  = (int*)take((size_t)NN * 4);
    int*            bsum = (int*)take(256 * 4);
    unsigned int*   pack = (unsigned int*)take((size_t)EE * 4 + 64);

    hipMemsetAsync(cnt, 0, (size_t)3 * NPAD * 4, stream);

    // ---- one prep launch (conversions + transposes + k2 + u/v + histogram) ----
    prep_kernel<<<PB8, 256, 0, stream>>>(
        embedding, scores, W1, W2, Wl, Wr, ln_g, ln_b, bl, br, We, be,
        emb_table, dst,
        embA, scoresb, W1T, W2T, WlrT, k2t, uvec, vvec, cnt);

    // ---- CSR build ----
    scan_part<<<NB, 256, 0, stream>>>(cnt, offb, bsum);
    scan_sums<<<1, 256, 0, stream>>>(bsum);
    scan_add<<<NB, 256, 0, stream>>>(offb, bsum, cur);
    fill_kernel<<<(EE + 255) / 256, 256, 0, stream>>>(src, dst, typ, cur, pack);

    // ---- MLP (full-grid): hpre = gelu(X@W1+b1)@W2+b2, stats fused ----
    dim3 g1(4 * HH / 128, NPAD / 128);
    mfma_gemm<1, 1, false, false><<<g1, 256, 0, stream>>>(
        embA, W1T, b1, Gch, nullptr, NN, HH, 4 * HH,
        nullptr, nullptr, nullptr, nullptr, nullptr);
    dim3 g2(HH / 128, NPAD / 128);
    mfma_gemm<0, 1, true, false><<<g2, 256, 0, stream>>>(
        Gch, W2T, b2, hpre, nullptr, NN, 4 * HH, HH,
        st1, st2, nullptr, nullptr, nullptr);

    // ---- q|k1 projection with fused LayerNorm; q->f16, k1->fp8 ----
    dim3 gq(512 / 128, NPAD / 128);
    mfma_gemm<0, 2, false, true><<<gq, 256, 0, stream>>>(
        hpre, WlrT, vvec, qbuf, k8, NN, HH, 512,
        nullptr, nullptr, st1, st2, uvec);

    // ---- fused edge phase (fp8 k gathers, defer-max) ----
    fused_edge_kernel<<<(NN + 3) / 4, 256, 0, stream>>>(
        qbuf, k8, k2t, offb, pack, scoresb, out);
}

// Round 16
// 357.239 us; speedup vs baseline: 1.0931x; 1.0016x over previous
//
#include <hip/hip_runtime.h>
#include <math.h>

#define NN 50000
#define EE 800000
#define HH 256
#define CC 64
#define NPAD 50048          // NN rounded to 128
#define NB 196              // scan blocks = ceil(NN/256)
#define QSCALE 0.09016843798f   // (1/16) * log2(e): folds 1/sqrt(H) and exp->exp2

typedef _Float16 f16x8 __attribute__((ext_vector_type(8)));
typedef _Float16 h2 __attribute__((ext_vector_type(2)));
typedef float f32x4 __attribute__((ext_vector_type(4)));
typedef float f32x2 __attribute__((ext_vector_type(2)));

// exact tanh-gelu via sigmoid identity: 0.5x(1+tanh(z)) = x / (1 + exp(-2z))
__device__ __forceinline__ float gelu_f(float x) {
    const float A = 2.302118074f;    // 2*log2(e)*sqrt(2/pi)
    const float B = 0.1029439565f;   // A*0.044715
    float u = x * fmaf(B, x * x, A);
    float den = 1.0f + exp2f(-u);
#if __has_builtin(__builtin_amdgcn_rcpf)
    return x * __builtin_amdgcn_rcpf(den);
#else
    return x / den;
#endif
}

__device__ __forceinline__ unsigned short f2h(float x) {
    _Float16 h = (_Float16)x;
    return __builtin_bit_cast(unsigned short, h);
}

__device__ __forceinline__ float h2f_(unsigned short u) {
    return (float)__builtin_bit_cast(_Float16, u);
}

__device__ __forceinline__ h2 u2h2(unsigned int u) {
    return __builtin_bit_cast(h2, u);
}

// float -> OCP fp8 e4m3fn (RNE via f16; flush |x|<2^-6 to 0; clamp to 448)
__device__ __forceinline__ unsigned char f2fp8(float v) {
    unsigned short h = f2h(v);
    unsigned s = (h >> 8) & 0x80u;
    int E = (h >> 10) & 31;
    unsigned M = h & 1023u;
    if (E <= 8) return (unsigned char)s;          // tiny -> signed zero
    unsigned m3 = M >> 7, rem = M & 127u;
    m3 += (rem > 64u) || (rem == 64u && (m3 & 1u));
    if (m3 == 8u) { m3 = 0u; ++E; }
    if (E > 23) { E = 23; m3 = 6u; }              // clamp to 448
    if (E == 23 && m3 == 7u) m3 = 6u;             // avoid NaN encoding
    return (unsigned char)(s | ((unsigned)(E - 8) << 3) | m3);
}

// 4x fp8 e4m3 (packed in u32) -> 4x f32 (scalar fallback only)
__device__ __forceinline__ void fp8x4_to_f32(unsigned w, float* o) {
    #pragma unroll
    for (int i = 0; i < 4; ++i) {
        unsigned u8 = (w >> (8 * i)) & 255u;
        unsigned short hb = (u8 & 0x7Fu)
            ? (unsigned short)(((u8 & 0x80u) << 8) | (((u8 & 0x7Fu) << 7) + 0x2000u))
            : (unsigned short)(u8 << 8);
        o[i] = h2f_(hb);
    }
}

__device__ __forceinline__ void gld_lds16(const void* g, void* l) {
    __builtin_amdgcn_global_load_lds(
        (const __attribute__((address_space(1))) unsigned int*)g,
        (__attribute__((address_space(3))) unsigned int*)l,
        16, 0, 0);
}

// T1: bijective XCD-aware remap (m204). HW round-robins consecutive flat ids
// across 8 XCDs; remap so each XCD owns a CONTIGUOUS run of logical tiles ->
// A row-panels become XCD-L2-resident across col-tiles.
__device__ __forceinline__ void xcd_tiles(int& tx, int& ty) {
    int gx = gridDim.x;
    int nwg = gx * gridDim.y;
    int flat = blockIdx.y * gx + blockIdx.x;     // hw dispatch order
    int q = nwg >> 3, r = nwg & 7;
    int xcd = flat & 7, j = flat >> 3;
    int idx = ((xcd < r) ? xcd * (q + 1) : r * (q + 1) + (xcd - r) * q) + j;
    tx = idx % gx;
    ty = idx / gx;
}

// ---------------------------------------------------------------------------
// C[M,Nc] = act(A_f16[M,K] @ BT_f16[Nc,K]^T + bias); 128x128 tile, 4 waves,
// 16x16x32 f16 MFMA. BK=32 double-buffered in 32KB LDS; stage(next) issued
// before compute(cur), one barrier per K-step. Slot-rotation swizzle keeps
// ds_read_b128 at the free 2-way level. XCD-swizzled tile assignment (T1).
// OUTMODE: 0 = f32 C, 1 = f16 C, 2 = split (col<256 -> f16 q stride 256;
//          col>=256 -> fp8 e4m3 into kout stride 256).
// STATS:  per-row sum/sumsq atomics into st1/st2.
// LNFOLD: out = inv*raw - inv*mu*u[col] + bias[col], mu/inv from rs1/rs2.
// ---------------------------------------------------------------------------
template<int ACT, int OUTMODE, bool STATS, bool LNFOLD>
__global__ __launch_bounds__(256) void mfma_gemm(
    const unsigned short* __restrict__ A,
    const unsigned short* __restrict__ BT,
    const float* __restrict__ bias,
    void* __restrict__ C,
    unsigned char* __restrict__ kout,
    int M, int K, int Nc,
    float* __restrict__ st1, float* __restrict__ st2,
    const float* __restrict__ rs1, const float* __restrict__ rs2,
    const float* __restrict__ uvec)
{
    __shared__ __align__(16) unsigned char lds[32768]; // 2 bufs x (A 8K | B 8K)
    const int t    = threadIdx.x;
    const int lane = t & 63;
    const int wv   = t >> 6;
    const int wr   = wv >> 1, wc = wv & 1;
    const int l16  = lane & 15;
    const int l4   = lane >> 4;
    int tx, ty;
    xcd_tiles(tx, ty);
    const int row0 = ty * 128;
    const int col0 = tx * 128;

    f32x4 acc[4][4] = {};

    // staging: thread t covers rows {srow32, 64+srow32}, slot sslot (16B)
    const int srow32 = t >> 2;               // 0..63
    const int sslot  = t & 3;
    const int gchunk = (sslot - ((srow32 >> 1) & 3)) & 3;  // global chunk at this slot

    const unsigned short* Ab = A  + (size_t)row0 * K;
    const unsigned short* Bb = BT + (size_t)col0 * K;

    auto stage = [&](int p, int k0) {
        #pragma unroll
        for (int i = 0; i < 2; ++i)
            gld_lds16(Ab + (size_t)(i * 64 + srow32) * K + k0 + gchunk * 8,
                      &lds[p * 16384 + i * 4096 + t * 16]);
        #pragma unroll
        for (int i = 0; i < 2; ++i)
            gld_lds16(Bb + (size_t)(i * 64 + srow32) * K + k0 + gchunk * 8,
                      &lds[p * 16384 + 8192 + i * 4096 + t * 16]);
    };

    stage(0, 0);
    __syncthreads();                         // drain prologue stage
    int p = 0;
    for (int k0 = 0; k0 < K; k0 += 32) {
        if (k0 + 32 < K) stage(p ^ 1, k0 + 32);   // prefetch next K-step

        f16x8 af[4], bf[4];
        #pragma unroll
        for (int m = 0; m < 4; ++m) {
            int r = wr * 64 + m * 16 + l16;
            int slot = (l4 + (r >> 1)) & 3;
            af[m] = *reinterpret_cast<const f16x8*>(&lds[p * 16384 + r * 64 + slot * 16]);
        }
        #pragma unroll
        for (int n = 0; n < 4; ++n) {
            int r = wc * 64 + n * 16 + l16;
            int slot = (l4 + (r >> 1)) & 3;
            bf[n] = *reinterpret_cast<const f16x8*>(&lds[p * 16384 + 8192 + r * 64 + slot * 16]);
        }
        #pragma unroll
        for (int m = 0; m < 4; ++m)
            #pragma unroll
            for (int n = 0; n < 4; ++n)
                acc[m][n] = __builtin_amdgcn_mfma_f32_16x16x32_f16(
                    af[m], bf[n], acc[m][n], 0, 0, 0);

        __syncthreads();   // next stage landed (overlapped with MFMAs above)
        p ^= 1;
    }

    float bv[4], uv_[4];
    #pragma unroll
    for (int n = 0; n < 4; ++n) {
        int col = col0 + wc * 64 + n * 16 + l16;
        bv[n] = bias[col];
        if (LNFOLD) uv_[n] = uvec[col];
    }

    #pragma unroll
    for (int m = 0; m < 4; ++m) {
        #pragma unroll
        for (int rg = 0; rg < 4; ++rg) {
            int row = row0 + wr * 64 + m * 16 + l4 * 4 + rg;
            float inv = 0.f, nmu = 0.f;
            if (LNFOLD) {
                float S1 = rs1[row], S2 = rs2[row];
                float mu = S1 * (1.0f / HH);
                float var = S2 * (1.0f / HH) - mu * mu;
                inv = rsqrtf(var + 1e-5f);
                nmu = inv * mu;
            }
            float s1l = 0.f, s2l = 0.f;
            #pragma unroll
            for (int n = 0; n < 4; ++n) {
                float v;
                if (LNFOLD) v = fmaf(inv, acc[m][n][rg], fmaf(-nmu, uv_[n], bv[n]));
                else        v = acc[m][n][rg] + bv[n];
                if (ACT) v = gelu_f(v);
                if (STATS) { s1l += v; s2l += v * v; }
                if (row < M) {
                    int col = col0 + wc * 64 + n * 16 + l16;
                    if (OUTMODE == 0)
                        ((float*)C)[(size_t)row * Nc + col] = v;
                    else if (OUTMODE == 1)
                        ((unsigned short*)C)[(size_t)row * Nc + col] = f2h(v);
                    else {
                        if (col < 256)
                            ((unsigned short*)C)[(size_t)row * 256 + col] = f2h(v);
                        else
                            kout[(size_t)row * 256 + (col - 256)] = f2fp8(v);
                    }
                }
            }
            if (STATS) {
                #pragma unroll
                for (int o = 1; o < 16; o <<= 1) {
                    s1l += __shfl_xor(s1l, o);
                    s2l += __shfl_xor(s2l, o);
                }
                if (l16 == 0 && row < M) {
                    atomicAdd(&st1[row], s1l);
                    atomicAdd(&st2[row], s2l);
                }
            }
        }
    }
}

// ---------------------------------------------------------------------------
// prep mega-kernel: f2h(embedding), f2h(scores), W1T, W2T, WlrT (g-folded,
// q-half scaled by QSCALE), k2 table, u/v fold vectors, AND the CSR histogram
// — one launch.
// ---------------------------------------------------------------------------
#define PB0 12500
#define PB1 (PB0 + 3125)
#define PB2 (PB1 + 1024)
#define PB3 (PB2 + 1024)
#define PB4 (PB3 + 256)
#define PB5 (PB4 + 256)
#define PB6 (PB5 + 3)
#define PB7 (PB6 + 2)
#define PB8 (PB7 + 3125)          // dst histogram
__global__ __launch_bounds__(256) void prep_kernel(
    const float* __restrict__ embedding, const float* __restrict__ scores,
    const float* __restrict__ W1, const float* __restrict__ W2,
    const float* __restrict__ Wl, const float* __restrict__ Wr,
    const float* __restrict__ ln_g, const float* __restrict__ ln_b,
    const float* __restrict__ bl, const float* __restrict__ br,
    const float* __restrict__ We, const float* __restrict__ be,
    const float* __restrict__ emb_table, const int* __restrict__ dst,
    unsigned short* __restrict__ embA, unsigned short* __restrict__ scoresb,
    unsigned short* __restrict__ W1T, unsigned short* __restrict__ W2T,
    unsigned short* __restrict__ WlrT, unsigned short* __restrict__ k2t,
    float* __restrict__ uvec, float* __restrict__ vvec, int* __restrict__ cnt)
{
    const int gb = blockIdx.x, t = threadIdx.x;
    if (gb < PB0) {
        int i = gb * 256 + t;
        float4 v = reinterpret_cast<const float4*>(embedding)[i];
        ushort4 o; o.x = f2h(v.x); o.y = f2h(v.y); o.z = f2h(v.z); o.w = f2h(v.w);
        reinterpret_cast<ushort4*>(embA)[i] = o;
    } else if (gb < PB1) {
        int i = (gb - PB0) * 256 + t;
        float4 v = reinterpret_cast<const float4*>(scores)[i];
        ushort4 o; o.x = f2h(v.x); o.y = f2h(v.y); o.z = f2h(v.z); o.w = f2h(v.w);
        reinterpret_cast<ushort4*>(scoresb)[i] = o;
    } else if (gb < PB2) {
        int o = (gb - PB1) * 256 + t;
        int c = o >> 8, r = o & 255;
        W1T[o] = f2h(W1[r * 1024 + c]);
    } else if (gb < PB3) {
        int o = (gb - PB2) * 256 + t;
        int c = o >> 10, r = o & 1023;
        W2T[o] = f2h(W2[r * 256 + c]);
    } else if (gb < PB4) {
        int o = (gb - PB3) * 256 + t;
        int c = o >> 8, r = o & 255;
        WlrT[o] = f2h(Wl[r * 256 + c] * ln_g[r] * QSCALE);
    } else if (gb < PB5) {
        int o = (gb - PB4) * 256 + t;
        int c = o >> 8, r = o & 255;
        WlrT[65536 + o] = f2h(Wr[r * 256 + c] * ln_g[r]);
    } else if (gb < PB6) {
        int ty = gb - PB5;
        float a = be[t];
        #pragma unroll
        for (int f = 0; f < 20; ++f)
            a += gelu_f(emb_table[ty * 20 + f]) * We[f * 256 + t];
        k2t[ty * 256 + t] = f2h(a);
    } else if (gb < PB7) {
        int c = (gb - PB6) * 256 + t;
        int cc = c & 255;
        const float* W = (c < 256) ? Wl : Wr;
        float u = 0.f, v = 0.f;
        for (int j = 0; j < 256; ++j) {
            float w = W[j * 256 + cc];
            u += ln_g[j] * w;
            v += ln_b[j] * w;
        }
        float sc = (c < 256) ? QSCALE : 1.0f;
        uvec[c] = u * sc;
        vvec[c] = (v + ((c < 256) ? bl[cc] : br[cc])) * sc;
    } else {
        int e = (gb - PB7) * 256 + t;
        if (e < EE) atomicAdd(&cnt[dst[e]], 1);
    }
}

// ---- CSR build ----
__global__ __launch_bounds__(256) void scan_part(
    const int* __restrict__ cnt, int* __restrict__ off, int* __restrict__ bsum)
{
    int b = blockIdx.x, t = threadIdx.x;
    int idx = b * 256 + t;
    int v = (idx < NN) ? cnt[idx] : 0;
    int inc = v;
    #pragma unroll
    for (int o = 1; o < 64; o <<= 1) {
        int u = __shfl_up(inc, o);
        if ((t & 63) >= o) inc += u;
    }
    __shared__ int wt[4];
    if ((t & 63) == 63) wt[t >> 6] = inc;
    __syncthreads();
    int wo = 0;
    #pragma unroll
    for (int w = 0; w < 4; ++w) if (w < (t >> 6)) wo += wt[w];
    if (idx < NN) off[idx] = wo + inc - v;
    if (t == 255) bsum[b] = wo + inc;
}

__global__ __launch_bounds__(256) void scan_sums(int* __restrict__ bsum)
{
    int t = threadIdx.x;
    int v = (t < NB) ? bsum[t] : 0;
    int inc = v;
    #pragma unroll
    for (int o = 1; o < 64; o <<= 1) {
        int u = __shfl_up(inc, o);
        if ((t & 63) >= o) inc += u;
    }
    __shared__ int wt[4];
    if ((t & 63) == 63) wt[t >> 6] = inc;
    __syncthreads();
    int wo = 0;
    #pragma unroll
    for (int w = 0; w < 4; ++w) if (w < (t >> 6)) wo += wt[w];
    if (t < NB) bsum[t] = wo + inc - v;
}

__global__ void scan_add(int* __restrict__ off, const int* __restrict__ bsum,
                         int* __restrict__ cur)
{
    int b = blockIdx.x, t = threadIdx.x;
    int idx = b * 256 + t;
    if (idx < NN) {
        int o = off[idx] + bsum[b];
        off[idx] = o;
        cur[idx] = o;
    }
    if (idx == 0) off[NN] = EE;
}

// pack entry = (src << 8) | ty  -> byte offset of the fp8 k-row, type in low bits
__global__ void fill_kernel(const int* __restrict__ src, const int* __restrict__ dst,
                            const int* __restrict__ typ, int* __restrict__ cur,
                            unsigned int* __restrict__ pack)
{
    int e = blockIdx.x * 256 + threadIdx.x;
    if (e < 16) pack[EE + e] = 0;
    if (e >= EE) return;
    int pos = atomicAdd(&cur[dst[e]], 1);
    pack[pos] = ((unsigned int)src[e] << 8) | (unsigned int)typ[e];
}

// ---------------------------------------------------------------------------
// fused per-dst attention (R15 + deep software pipeline):
// one wave per node; 2 edges per iteration; pack pairs read 4 iterations
// ahead (sequential ring), k/score gathers issued 2 iterations ahead — the
// pack->gather and gather->use dependent chains each span 2 iterations of
// compute, hiding L2/L3 gather latency. fp8 k gathers, exp2-domain online
// softmax with deferred rescale. Tail over-reads land in the 16 pad slots
// (or neighboring nodes' valid entries) and are masked with -inf.
// ---------------------------------------------------------------------------
__global__ __launch_bounds__(256) void fused_edge_kernel(
    const unsigned short* __restrict__ qbuf,    // f16 [NPAD][256]: q*QSCALE
    const unsigned char* __restrict__ k8,       // fp8 [NPAD][256]: k1 (g-folded)
    const unsigned short* __restrict__ k2t,     // f16 [3][256]
    const int* __restrict__ off, const unsigned int* __restrict__ pack,
    const unsigned short* __restrict__ scoresb, // f16 [NN][64]
    float* __restrict__ out)
{
    const int t = threadIdx.x, lane = t & 63;
    const int sub = lane & 31;
    const int g = lane >> 5;
    const int d = blockIdx.x * 4 + (t >> 6);
    if (d >= NN) return;
    const int beg = off[d], end = off[d + 1];
    if (beg == end) { out[(size_t)d * CC + lane] = 0.f; return; }

    // q slice: 8 f16 at dims [sub*8, sub*8+8) (duplicated across wave halves)
    uint4 qv = *reinterpret_cast<const uint4*>(
        (const char*)qbuf + (size_t)d * 512 + sub * 16);
    h2 q0 = u2h2(qv.x), q1 = u2h2(qv.y), q2 = u2h2(qv.z), q3 = u2h2(qv.w);
    f32x2 qp0 = {(float)q0[0], (float)q0[1]};
    f32x2 qp1 = {(float)q1[0], (float)q1[1]};
    f32x2 qp2 = {(float)q2[0], (float)q2[1]};
    f32x2 qp3 = {(float)q3[0], (float)q3[1]};

    // qe[ty] = q . k2t[ty] (f16 path, k2t exact)
    float qe0, qe1, qe2;
    {
        uint4 k0v = *reinterpret_cast<const uint4*>((const char*)k2t + 0 * 512 + sub * 16);
        uint4 k1v = *reinterpret_cast<const uint4*>((const char*)k2t + 1 * 512 + sub * 16);
        uint4 k2v = *reinterpret_cast<const uint4*>((const char*)k2t + 2 * 512 + sub * 16);
        auto dot16 = [&](uint4 kv) {
            h2 p = q0 * u2h2(kv.x) + q1 * u2h2(kv.y) + q2 * u2h2(kv.z) + q3 * u2h2(kv.w);
            return (float)p[0] + (float)p[1];
        };
        qe0 = dot16(k0v); qe1 = dot16(k1v); qe2 = dot16(k2v);
        #pragma unroll
        for (int o = 1; o < 32; o <<= 1) {
            qe0 += __shfl_xor(qe0, o);
            qe1 += __shfl_xor(qe1, o);
            qe2 += __shfl_xor(qe2, o);
        }
    }
    auto qsel = [&](unsigned pk) {
        int ty = pk & 3;
        return (ty == 0) ? qe0 : (ty == 1) ? qe1 : qe2;
    };
    auto dot8 = [&](uint2 kv) {
#if __has_builtin(__builtin_amdgcn_cvt_pk_f32_fp8)
        auto k0 = __builtin_amdgcn_cvt_pk_f32_fp8(kv.x, false);
        auto k1 = __builtin_amdgcn_cvt_pk_f32_fp8(kv.x, true);
        auto k2 = __builtin_amdgcn_cvt_pk_f32_fp8(kv.y, false);
        auto k3 = __builtin_amdgcn_cvt_pk_f32_fp8(kv.y, true);
        f32x2 s01 = qp0 * f32x2{k0[0], k0[1]} + qp1 * f32x2{k1[0], k1[1]};
        f32x2 s23 = qp2 * f32x2{k2[0], k2[1]} + qp3 * f32x2{k3[0], k3[1]};
        f32x2 s = s01 + s23;
        return s[0] + s[1];
#else
        float kf[8];
        fp8x4_to_f32(kv.x, kf);
        fp8x4_to_f32(kv.y, kf + 4);
        float u0 = fmaf(qp0[1], kf[1], qp0[0] * kf[0]);
        float u1 = fmaf(qp1[1], kf[3], qp1[0] * kf[2]);
        float u2 = fmaf(qp2[1], kf[5], qp2[0] * kf[4]);
        float u3 = fmaf(qp3[1], kf[7], qp3[0] * kf[6]);
        return (u0 + u1) + (u2 + u3);
#endif
    };
    auto gath = [&](unsigned pA, unsigned pB, uint2& kv_, float& sA, float& sB) {
        kv_ = *reinterpret_cast<const uint2*>(k8 + ((g ? pB : pA) & ~3u) + sub * 8);
        sA = h2f_(scoresb[((pA & ~3u) >> 2) + lane]);
        sB = h2f_(scoresb[((pB & ~3u) >> 2) + lane]);
    };

    // pipeline prologue: pack ring depth 4 (pairs), gather sets depth 2.
    // Over-reads past `end` hit neighbors' valid entries or the pad slots.
    unsigned pA0 = pack[beg],     pB0 = pack[beg + 1];
    unsigned pA1 = pack[beg + 2], pB1 = pack[beg + 3];
    unsigned pA2 = pack[beg + 4], pB2 = pack[beg + 5];
    unsigned pA3 = pack[beg + 6], pB3 = pack[beg + 7];
    uint2 kv0, kv1;
    float sA0, sB0, sA1, sB1;
    gath(pA0, pB0, kv0, sA0, sB0);
    gath(pA1, pB1, kv1, sA1, sB1);

    float m = -INFINITY, s = 0.f, acc = 0.f;

    for (int i = beg; i < end; i += 2) {
        // pack pair 4 iterations ahead (sequential, cheap)
        unsigned nA = pack[i + 8], nB = pack[i + 9];
        // gathers 2 iterations ahead, using pack pair loaded 2 iters ago
        uint2 nkv; float nsA, nsB;
        gath(pA2, pB2, nkv, nsA, nsB);

        float a = dot8(kv0);
        #pragma unroll
        for (int o = 1; o < 32; o <<= 1) a += __shfl_xor(a, o);
        float other = __shfl_xor(a, 32);
        float aA = (g ? other : a) + qsel(pA0);
        float aB = (g ? a : other) + qsel(pB0);
        if (i + 1 >= end) aB = -INFINITY;     // odd tail (garbage masked)

        // T13 defer-max: rescale only when the running max grows by >11.5
        float bm = fmaxf(aA, aB);             // wave-uniform
        if (bm > m + 11.5f) {
            float c_ = exp2f(m - bm);         // first iter: exp2(-inf)=0
            s *= c_;
            acc *= c_;
            m = bm;
        }
        float w0 = exp2f(aA - m);
        float w1 = exp2f(aB - m);
        s += w0 + w1;
        acc = fmaf(w0, sA0, fmaf(w1, sB0, acc));

        // rotate pipeline
        pA0 = pA1; pB0 = pB1; kv0 = kv1; sA0 = sA1; sB0 = sB1;
        pA1 = pA2; pB1 = pB2; kv1 = nkv; sA1 = nsA; sB1 = nsB;
        pA2 = pA3; pB2 = pB3;
        pA3 = nA;  pB3 = nB;
    }
    out[(size_t)d * CC + lane] = acc / s;
}

extern "C" void kernel_launch(void* const* d_in, const int* in_sizes, int n_in,
                              void* d_out, int out_size, void* d_ws, size_t ws_size,
                              hipStream_t stream) {
    const float* embedding = (const float*)d_in[0];
    const float* scores    = (const float*)d_in[1];
    const int*   src       = (const int*)d_in[2];
    const int*   dst       = (const int*)d_in[3];
    const int*   typ       = (const int*)d_in[4];
    const float* W1  = (const float*)d_in[5];
    const float* b1  = (const float*)d_in[6];
    const float* W2  = (const float*)d_in[7];
    const float* b2  = (const float*)d_in[8];
    const float* ln_g = (const float*)d_in[9];
    const float* ln_b = (const float*)d_in[10];
    const float* Wl  = (const float*)d_in[11];
    const float* bl  = (const float*)d_in[12];
    const float* Wr  = (const float*)d_in[13];
    const float* br  = (const float*)d_in[14];
    const float* We  = (const float*)d_in[15];
    const float* be  = (const float*)d_in[16];
    const float* emb_table = (const float*)d_in[17];
    float* out = (float*)d_out;
    (void)in_sizes; (void)n_in; (void)out_size; (void)ws_size;

    // ---- workspace carve-up (256-aligned chunks) ----
    char* w = (char*)d_ws;
    auto take = [&](size_t bytes) {
        char* p = w;
        w += (bytes + 255) & ~(size_t)255;
        return p;
    };
    unsigned short* embA = (unsigned short*)take((size_t)NPAD * HH * 2);
    unsigned short* hpre = (unsigned short*)take((size_t)NPAD * HH * 2);
    // BIG buffer: Gch [NPAD][1024] f16 during the MLP; afterwards its first
    // NPAD*512B serve as qbuf [NPAD][256] f16 and the next NPAD*256B as the
    // fp8 k-buffer (Gch dead once GEMM2 reads it).
    unsigned short* Gch  = (unsigned short*)take((size_t)NPAD * 1024 * 2);
    unsigned short* qbuf = Gch;
    unsigned char*  k8   = (unsigned char*)(Gch + (size_t)NPAD * 256);
    unsigned short* W1T  = (unsigned short*)take((size_t)4 * HH * HH * 2);
    unsigned short* W2T  = (unsigned short*)take((size_t)HH * 4 * HH * 2);
    unsigned short* WlrT = (unsigned short*)take((size_t)512 * HH * 2);
    unsigned short* k2t  = (unsigned short*)take(2048);
    unsigned short* scoresb = (unsigned short*)take((size_t)NN * CC * 2);
    float*          uvec = (float*)take(512 * 4);
    float*          vvec = (float*)take(512 * 4);
    int*            cnt  = (int*)take((size_t)NPAD * 4);
    float*          st1  = (float*)take((size_t)NPAD * 4);
    float*          st2  = (float*)take((size_t)NPAD * 4);
    int*            offb = (int*)take((size_t)(NN + 1) * 4);
    int*            cur  = (int*)take((size_t)NN * 4);
    int*            bsum = (int*)take(256 * 4);
    unsigned int*   pack = (unsigned int*)take((size_t)EE * 4 + 64);

    hipMemsetAsync(cnt, 0, (size_t)3 * NPAD * 4, stream);

    // ---- one prep launch (conversions + transposes + k2 + u/v + histogram) ----
    prep_kernel<<<PB8, 256, 0, stream>>>(
        embedding, scores, W1, W2, Wl, Wr, ln_g, ln_b, bl, br, We, be,
        emb_table, dst,
        embA, scoresb, W1T, W2T, WlrT, k2t, uvec, vvec, cnt);

    // ---- CSR build ----
    scan_part<<<NB, 256, 0, stream>>>(cnt, offb, bsum);
    scan_sums<<<1, 256, 0, stream>>>(bsum);
    scan_add<<<NB, 256, 0, stream>>>(offb, bsum, cur);
    fill_kernel<<<(EE + 255) / 256, 256, 0, stream>>>(src, dst, typ, cur, pack);

    // ---- MLP (full-grid): hpre = gelu(X@W1+b1)@W2+b2, stats fused ----
    dim3 g1(4 * HH / 128, NPAD / 128);
    mfma_gemm<1, 1, false, false><<<g1, 256, 0, stream>>>(
        embA, W1T, b1, Gch, nullptr, NN, HH, 4 * HH,
        nullptr, nullptr, nullptr, nullptr, nullptr);
    dim3 g2(HH / 128, NPAD / 128);
    mfma_gemm<0, 1, true, false><<<g2, 256, 0, stream>>>(
        Gch, W2T, b2, hpre, nullptr, NN, 4 * HH, HH,
        st1, st2, nullptr, nullptr, nullptr);

    // ---- q|k1 projection with fused LayerNorm; q->f16, k1->fp8 ----
    dim3 gq(512 / 128, NPAD / 128);
    mfma_gemm<0, 2, false, true><<<gq, 256, 0, stream>>>(
        hpre, WlrT, vvec, qbuf, k8, NN, HH, 512,
        nullptr, nullptr, st1, st2, uvec);

    // ---- fused edge phase (fp8 k gathers, defer-max, 2-deep pipeline) ----
    fused_edge_kernel<<<(NN + 3) / 4, 256, 0, stream>>>(
        qbuf, k8, k2t, offb, pack, scoresb, out);
}

// Round 17
// 351.123 us; speedup vs baseline: 1.1122x; 1.0174x over previous
//
#include <hip/hip_runtime.h>
#include <math.h>

#define NN 50000
#define EE 800000
#define HH 256
#define CC 64
#define NPAD 50048          // NN rounded to 128
#define NB 196              // scan blocks = ceil(NN/256)
#define QSCALE 0.09016843798f   // (1/16) * log2(e): folds 1/sqrt(H) and exp->exp2

typedef _Float16 f16x8 __attribute__((ext_vector_type(8)));
typedef _Float16 h2 __attribute__((ext_vector_type(2)));
typedef float f32x4 __attribute__((ext_vector_type(4)));
typedef float f32x2 __attribute__((ext_vector_type(2)));

// exact tanh-gelu via sigmoid identity: 0.5x(1+tanh(z)) = x / (1 + exp(-2z))
__device__ __forceinline__ float gelu_f(float x) {
    const float A = 2.302118074f;    // 2*log2(e)*sqrt(2/pi)
    const float B = 0.1029439565f;   // A*0.044715
    float u = x * fmaf(B, x * x, A);
    float den = 1.0f + exp2f(-u);
#if __has_builtin(__builtin_amdgcn_rcpf)
    return x * __builtin_amdgcn_rcpf(den);
#else
    return x / den;
#endif
}

__device__ __forceinline__ unsigned short f2h(float x) {
    _Float16 h = (_Float16)x;
    return __builtin_bit_cast(unsigned short, h);
}

__device__ __forceinline__ float h2f_(unsigned short u) {
    return (float)__builtin_bit_cast(_Float16, u);
}

__device__ __forceinline__ h2 u2h2(unsigned int u) {
    return __builtin_bit_cast(h2, u);
}

// float -> OCP fp8 e4m3fn (RNE via f16; flush |x|<2^-6 to 0; clamp to 448)
__device__ __forceinline__ unsigned char f2fp8(float v) {
    unsigned short h = f2h(v);
    unsigned s = (h >> 8) & 0x80u;
    int E = (h >> 10) & 31;
    unsigned M = h & 1023u;
    if (E <= 8) return (unsigned char)s;          // tiny -> signed zero
    unsigned m3 = M >> 7, rem = M & 127u;
    m3 += (rem > 64u) || (rem == 64u && (m3 & 1u));
    if (m3 == 8u) { m3 = 0u; ++E; }
    if (E > 23) { E = 23; m3 = 6u; }              // clamp to 448
    if (E == 23 && m3 == 7u) m3 = 6u;             // avoid NaN encoding
    return (unsigned char)(s | ((unsigned)(E - 8) << 3) | m3);
}

// 4x fp8 e4m3 (packed in u32) -> 4x f32 (scalar fallback only)
__device__ __forceinline__ void fp8x4_to_f32(unsigned w, float* o) {
    #pragma unroll
    for (int i = 0; i < 4; ++i) {
        unsigned u8 = (w >> (8 * i)) & 255u;
        unsigned short hb = (u8 & 0x7Fu)
            ? (unsigned short)(((u8 & 0x80u) << 8) | (((u8 & 0x7Fu) << 7) + 0x2000u))
            : (unsigned short)(u8 << 8);
        o[i] = h2f_(hb);
    }
}

__device__ __forceinline__ void gld_lds16(const void* g, void* l) {
    __builtin_amdgcn_global_load_lds(
        (const __attribute__((address_space(1))) unsigned int*)g,
        (__attribute__((address_space(3))) unsigned int*)l,
        16, 0, 0);
}

// ---- scan bodies (shared by standalone + piggybacked forms) ----
__device__ void scan_part_body(int b, int t, const int* __restrict__ cnt,
                               int* __restrict__ off, int* __restrict__ bsum,
                               int* wt)
{
    int idx = b * 256 + t;
    int v = (idx < NN) ? cnt[idx] : 0;
    int inc = v;
    #pragma unroll
    for (int o = 1; o < 64; o <<= 1) {
        int u = __shfl_up(inc, o);
        if ((t & 63) >= o) inc += u;
    }
    if ((t & 63) == 63) wt[t >> 6] = inc;
    __syncthreads();
    int wo = 0;
    #pragma unroll
    for (int w = 0; w < 4; ++w) if (w < (t >> 6)) wo += wt[w];
    if (idx < NN) off[idx] = wo + inc - v;
    if (t == 255) bsum[b] = wo + inc;
}

__device__ void scan_sums_body(int t, int* __restrict__ bsum, int* wt)
{
    int v = (t < NB) ? bsum[t] : 0;
    int inc = v;
    #pragma unroll
    for (int o = 1; o < 64; o <<= 1) {
        int u = __shfl_up(inc, o);
        if ((t & 63) >= o) inc += u;
    }
    if ((t & 63) == 63) wt[t >> 6] = inc;
    __syncthreads();
    int wo = 0;
    #pragma unroll
    for (int w = 0; w < 4; ++w) if (w < (t >> 6)) wo += wt[w];
    if (t < NB) bsum[t] = wo + inc - v;
}

__device__ void scan_add_body(int b, int t, int* __restrict__ off,
                              const int* __restrict__ bsum, int* __restrict__ cur)
{
    int idx = b * 256 + t;
    if (idx < NN) {
        int o = off[idx] + bsum[b];
        off[idx] = o;
        cur[idx] = o;
    }
    if (idx == 0) off[NN] = EE;
}

// T1: bijective XCD-aware remap (m204) over the GEMM-only flat range.
__device__ __forceinline__ void xcd_tiles(int flat, int ngemm, int gx,
                                          int& tx, int& ty) {
    int q = ngemm >> 3, r = ngemm & 7;
    int xcd = flat & 7, j = flat >> 3;
    int idx = ((xcd < r) ? xcd * (q + 1) : r * (q + 1) + (xcd - r) * q) + j;
    tx = idx % gx;
    ty = idx / gx;
}

// ---------------------------------------------------------------------------
// C[M,Nc] = act(A_f16[M,K] @ BT_f16[Nc,K]^T + bias); 128x128 tile, 4 waves,
// 16x16x32 f16 MFMA. BK=32 double-buffered in 32KB LDS; stage(next) issued
// before compute(cur), one barrier per K-step. Slot-rotation swizzle keeps
// ds_read_b128 at the free 2-way level. XCD-swizzled tile assignment (T1).
// SIDE work rides in extra grid blocks (blockIdx.y >= ny): 1 = scan_part,
// 2 = scan_sums, 3 = scan_add — the CSR scan hides inside the GEMM launches.
// OUTMODE: 0 = f32 C, 1 = f16 C, 2 = split (col<256 -> f16 q stride 256;
//          col>=256 -> fp8 e4m3 into kout stride 256).
// STATS:  per-row sum/sumsq atomics into st1/st2.
// LNFOLD: out = inv*raw - inv*mu*u[col] + bias[col], mu/inv from rs1/rs2.
// ---------------------------------------------------------------------------
template<int ACT, int OUTMODE, bool STATS, bool LNFOLD, int SIDE>
__global__ __launch_bounds__(256) void mfma_gemm(
    const unsigned short* __restrict__ A,
    const unsigned short* __restrict__ BT,
    const float* __restrict__ bias,
    void* __restrict__ C,
    unsigned char* __restrict__ kout,
    int M, int K, int Nc, int ny,
    float* __restrict__ st1, float* __restrict__ st2,
    const float* __restrict__ rs1, const float* __restrict__ rs2,
    const float* __restrict__ uvec,
    int* __restrict__ sc0, int* __restrict__ sc1,
    int* __restrict__ sc2, int* __restrict__ sc3)
{
    __shared__ __align__(16) unsigned char lds[32768]; // 2 bufs x (A 8K | B 8K)
    const int gx = gridDim.x;
    const int flat = blockIdx.y * gx + blockIdx.x;
    const int ngemm = gx * ny;
    if (SIDE && flat >= ngemm) {                 // block-uniform branch
        int sb = flat - ngemm;
        int* wt = (int*)lds;
        if (SIDE == 1) { if (sb < NB) scan_part_body(sb, threadIdx.x, sc0, sc1, sc2, wt); }
        else if (SIDE == 2) { if (sb < 1) scan_sums_body(threadIdx.x, sc2, wt); }
        else if (SIDE == 3) { if (sb < NB) scan_add_body(sb, threadIdx.x, sc1, sc2, sc3); }
        return;
    }

    const int t    = threadIdx.x;
    const int lane = t & 63;
    const int wv   = t >> 6;
    const int wr   = wv >> 1, wc = wv & 1;
    const int l16  = lane & 15;
    const int l4   = lane >> 4;
    int tx, ty;
    xcd_tiles(flat, ngemm, gx, tx, ty);
    const int row0 = ty * 128;
    const int col0 = tx * 128;

    f32x4 acc[4][4] = {};

    // staging: thread t covers rows {srow32, 64+srow32}, slot sslot (16B)
    const int srow32 = t >> 2;               // 0..63
    const int sslot  = t & 3;
    const int gchunk = (sslot - ((srow32 >> 1) & 3)) & 3;  // global chunk at this slot

    const unsigned short* Ab = A  + (size_t)row0 * K;
    const unsigned short* Bb = BT + (size_t)col0 * K;

    auto stage = [&](int p, int k0) {
        #pragma unroll
        for (int i = 0; i < 2; ++i)
            gld_lds16(Ab + (size_t)(i * 64 + srow32) * K + k0 + gchunk * 8,
                      &lds[p * 16384 + i * 4096 + t * 16]);
        #pragma unroll
        for (int i = 0; i < 2; ++i)
            gld_lds16(Bb + (size_t)(i * 64 + srow32) * K + k0 + gchunk * 8,
                      &lds[p * 16384 + 8192 + i * 4096 + t * 16]);
    };

    stage(0, 0);
    __syncthreads();                         // drain prologue stage
    int p = 0;
    for (int k0 = 0; k0 < K; k0 += 32) {
        if (k0 + 32 < K) stage(p ^ 1, k0 + 32);   // prefetch next K-step

        f16x8 af[4], bf[4];
        #pragma unroll
        for (int m = 0; m < 4; ++m) {
            int r = wr * 64 + m * 16 + l16;
            int slot = (l4 + (r >> 1)) & 3;
            af[m] = *reinterpret_cast<const f16x8*>(&lds[p * 16384 + r * 64 + slot * 16]);
        }
        #pragma unroll
        for (int n = 0; n < 4; ++n) {
            int r = wc * 64 + n * 16 + l16;
            int slot = (l4 + (r >> 1)) & 3;
            bf[n] = *reinterpret_cast<const f16x8*>(&lds[p * 16384 + 8192 + r * 64 + slot * 16]);
        }
        #pragma unroll
        for (int m = 0; m < 4; ++m)
            #pragma unroll
            for (int n = 0; n < 4; ++n)
                acc[m][n] = __builtin_amdgcn_mfma_f32_16x16x32_f16(
                    af[m], bf[n], acc[m][n], 0, 0, 0);

        __syncthreads();   // next stage landed (overlapped with MFMAs above)
        p ^= 1;
    }

    float bv[4], uv_[4];
    #pragma unroll
    for (int n = 0; n < 4; ++n) {
        int col = col0 + wc * 64 + n * 16 + l16;
        bv[n] = bias[col];
        if (LNFOLD) uv_[n] = uvec[col];
    }

    #pragma unroll
    for (int m = 0; m < 4; ++m) {
        #pragma unroll
        for (int rg = 0; rg < 4; ++rg) {
            int row = row0 + wr * 64 + m * 16 + l4 * 4 + rg;
            float inv = 0.f, nmu = 0.f;
            if (LNFOLD) {
                float S1 = rs1[row], S2 = rs2[row];
                float mu = S1 * (1.0f / HH);
                float var = S2 * (1.0f / HH) - mu * mu;
                inv = rsqrtf(var + 1e-5f);
                nmu = inv * mu;
            }
            float s1l = 0.f, s2l = 0.f;
            #pragma unroll
            for (int n = 0; n < 4; ++n) {
                float v;
                if (LNFOLD) v = fmaf(inv, acc[m][n][rg], fmaf(-nmu, uv_[n], bv[n]));
                else        v = acc[m][n][rg] + bv[n];
                if (ACT) v = gelu_f(v);
                if (STATS) { s1l += v; s2l += v * v; }
                if (row < M) {
                    int col = col0 + wc * 64 + n * 16 + l16;
                    if (OUTMODE == 0)
                        ((float*)C)[(size_t)row * Nc + col] = v;
                    else if (OUTMODE == 1)
                        ((unsigned short*)C)[(size_t)row * Nc + col] = f2h(v);
                    else {
                        if (col < 256)
                            ((unsigned short*)C)[(size_t)row * 256 + col] = f2h(v);
                        else
                            kout[(size_t)row * 256 + (col - 256)] = f2fp8(v);
                    }
                }
            }
            if (STATS) {
                #pragma unroll
                for (int o = 1; o < 16; o <<= 1) {
                    s1l += __shfl_xor(s1l, o);
                    s2l += __shfl_xor(s2l, o);
                }
                if (l16 == 0 && row < M) {
                    atomicAdd(&st1[row], s1l);
                    atomicAdd(&st2[row], s2l);
                }
            }
        }
    }
}

// ---------------------------------------------------------------------------
// prep mega-kernel: f2h(embedding), f2h(scores), W1T, W2T, WlrT (g-folded,
// q-half scaled by QSCALE), k2 table, u/v fold vectors, AND the CSR histogram
// — one launch.
// ---------------------------------------------------------------------------
#define PB0 12500
#define PB1 (PB0 + 3125)
#define PB2 (PB1 + 1024)
#define PB3 (PB2 + 1024)
#define PB4 (PB3 + 256)
#define PB5 (PB4 + 256)
#define PB6 (PB5 + 3)
#define PB7 (PB6 + 2)
#define PB8 (PB7 + 3125)          // dst histogram
__global__ __launch_bounds__(256) void prep_kernel(
    const float* __restrict__ embedding, const float* __restrict__ scores,
    const float* __restrict__ W1, const float* __restrict__ W2,
    const float* __restrict__ Wl, const float* __restrict__ Wr,
    const float* __restrict__ ln_g, const float* __restrict__ ln_b,
    const float* __restrict__ bl, const float* __restrict__ br,
    const float* __restrict__ We, const float* __restrict__ be,
    const float* __restrict__ emb_table, const int* __restrict__ dst,
    unsigned short* __restrict__ embA, unsigned short* __restrict__ scoresb,
    unsigned short* __restrict__ W1T, unsigned short* __restrict__ W2T,
    unsigned short* __restrict__ WlrT, unsigned short* __restrict__ k2t,
    float* __restrict__ uvec, float* __restrict__ vvec, int* __restrict__ cnt)
{
    const int gb = blockIdx.x, t = threadIdx.x;
    if (gb < PB0) {
        int i = gb * 256 + t;
        float4 v = reinterpret_cast<const float4*>(embedding)[i];
        ushort4 o; o.x = f2h(v.x); o.y = f2h(v.y); o.z = f2h(v.z); o.w = f2h(v.w);
        reinterpret_cast<ushort4*>(embA)[i] = o;
    } else if (gb < PB1) {
        int i = (gb - PB0) * 256 + t;
        float4 v = reinterpret_cast<const float4*>(scores)[i];
        ushort4 o; o.x = f2h(v.x); o.y = f2h(v.y); o.z = f2h(v.z); o.w = f2h(v.w);
        reinterpret_cast<ushort4*>(scoresb)[i] = o;
    } else if (gb < PB2) {
        int o = (gb - PB1) * 256 + t;
        int c = o >> 8, r = o & 255;
        W1T[o] = f2h(W1[r * 1024 + c]);
    } else if (gb < PB3) {
        int o = (gb - PB2) * 256 + t;
        int c = o >> 10, r = o & 1023;
        W2T[o] = f2h(W2[r * 256 + c]);
    } else if (gb < PB4) {
        int o = (gb - PB3) * 256 + t;
        int c = o >> 8, r = o & 255;
        WlrT[o] = f2h(Wl[r * 256 + c] * ln_g[r] * QSCALE);
    } else if (gb < PB5) {
        int o = (gb - PB4) * 256 + t;
        int c = o >> 8, r = o & 255;
        WlrT[65536 + o] = f2h(Wr[r * 256 + c] * ln_g[r]);
    } else if (gb < PB6) {
        int ty = gb - PB5;
        float a = be[t];
        #pragma unroll
        for (int f = 0; f < 20; ++f)
            a += gelu_f(emb_table[ty * 20 + f]) * We[f * 256 + t];
        k2t[ty * 256 + t] = f2h(a);
    } else if (gb < PB7) {
        int c = (gb - PB6) * 256 + t;
        int cc = c & 255;
        const float* W = (c < 256) ? Wl : Wr;
        float u = 0.f, v = 0.f;
        for (int j = 0; j < 256; ++j) {
            float w = W[j * 256 + cc];
            u += ln_g[j] * w;
            v += ln_b[j] * w;
        }
        float sc = (c < 256) ? QSCALE : 1.0f;
        uvec[c] = u * sc;
        vvec[c] = (v + ((c < 256) ? bl[cc] : br[cc])) * sc;
    } else {
        int e = (gb - PB7) * 256 + t;
        if (e < EE) atomicAdd(&cnt[dst[e]], 1);
    }
}

// pack entry = (src << 8) | ty  -> byte offset of the fp8 k-row, type in low bits
__global__ void fill_kernel(const int* __restrict__ src, const int* __restrict__ dst,
                            const int* __restrict__ typ, int* __restrict__ cur,
                            unsigned int* __restrict__ pack)
{
    int e = blockIdx.x * 256 + threadIdx.x;
    if (e < 16) pack[EE + e] = 0;
    if (e >= EE) return;
    int pos = atomicAdd(&cur[dst[e]], 1);
    pack[pos] = ((unsigned int)src[e] << 8) | (unsigned int)typ[e];
}

// ---------------------------------------------------------------------------
// fused per-dst attention (R15 form — proven best): one wave per node; 2
// edges in flight, shared 32-lane dot/reduce, fp8 k gathers, exp2-domain
// online softmax with deferred rescale, qe prologue, depth-1 prefetch.
// ---------------------------------------------------------------------------
__global__ __launch_bounds__(256) void fused_edge_kernel(
    const unsigned short* __restrict__ qbuf,    // f16 [NPAD][256]: q*QSCALE
    const unsigned char* __restrict__ k8,       // fp8 [NPAD][256]: k1 (g-folded)
    const unsigned short* __restrict__ k2t,     // f16 [3][256]
    const int* __restrict__ off, const unsigned int* __restrict__ pack,
    const unsigned short* __restrict__ scoresb, // f16 [NN][64]
    float* __restrict__ out)
{
    const int t = threadIdx.x, lane = t & 63;
    const int sub = lane & 31;
    const int g = lane >> 5;
    const int d = blockIdx.x * 4 + (t >> 6);
    if (d >= NN) return;
    const int beg = off[d], end = off[d + 1];
    if (beg == end) { out[(size_t)d * CC + lane] = 0.f; return; }

    // q slice: 8 f16 at dims [sub*8, sub*8+8) (duplicated across wave halves)
    uint4 qv = *reinterpret_cast<const uint4*>(
        (const char*)qbuf + (size_t)d * 512 + sub * 16);
    h2 q0 = u2h2(qv.x), q1 = u2h2(qv.y), q2 = u2h2(qv.z), q3 = u2h2(qv.w);
    f32x2 qp0 = {(float)q0[0], (float)q0[1]};
    f32x2 qp1 = {(float)q1[0], (float)q1[1]};
    f32x2 qp2 = {(float)q2[0], (float)q2[1]};
    f32x2 qp3 = {(float)q3[0], (float)q3[1]};

    // qe[ty] = q . k2t[ty] (f16 path, k2t exact)
    float qe0, qe1, qe2;
    {
        uint4 k0v = *reinterpret_cast<const uint4*>((const char*)k2t + 0 * 512 + sub * 16);
        uint4 k1v = *reinterpret_cast<const uint4*>((const char*)k2t + 1 * 512 + sub * 16);
        uint4 k2v = *reinterpret_cast<const uint4*>((const char*)k2t + 2 * 512 + sub * 16);
        auto dot16 = [&](uint4 kv) {
            h2 p = q0 * u2h2(kv.x) + q1 * u2h2(kv.y) + q2 * u2h2(kv.z) + q3 * u2h2(kv.w);
            return (float)p[0] + (float)p[1];
        };
        qe0 = dot16(k0v); qe1 = dot16(k1v); qe2 = dot16(k2v);
        #pragma unroll
        for (int o = 1; o < 32; o <<= 1) {
            qe0 += __shfl_xor(qe0, o);
            qe1 += __shfl_xor(qe1, o);
            qe2 += __shfl_xor(qe2, o);
        }
    }
    auto qsel = [&](unsigned pk) {
        int ty = pk & 3;
        return (ty == 0) ? qe0 : (ty == 1) ? qe1 : qe2;
    };
    auto dot8 = [&](uint2 kv) {
#if __has_builtin(__builtin_amdgcn_cvt_pk_f32_fp8)
        auto k0 = __builtin_amdgcn_cvt_pk_f32_fp8(kv.x, false);
        auto k1 = __builtin_amdgcn_cvt_pk_f32_fp8(kv.x, true);
        auto k2 = __builtin_amdgcn_cvt_pk_f32_fp8(kv.y, false);
        auto k3 = __builtin_amdgcn_cvt_pk_f32_fp8(kv.y, true);
        f32x2 s01 = qp0 * f32x2{k0[0], k0[1]} + qp1 * f32x2{k1[0], k1[1]};
        f32x2 s23 = qp2 * f32x2{k2[0], k2[1]} + qp3 * f32x2{k3[0], k3[1]};
        f32x2 s = s01 + s23;
        return s[0] + s[1];
#else
        float kf[8];
        fp8x4_to_f32(kv.x, kf);
        fp8x4_to_f32(kv.y, kf + 4);
        float u0 = fmaf(qp0[1], kf[1], qp0[0] * kf[0]);
        float u1 = fmaf(qp1[1], kf[3], qp1[0] * kf[2]);
        float u2 = fmaf(qp2[1], kf[5], qp2[0] * kf[4]);
        float u3 = fmaf(qp3[1], kf[7], qp3[0] * kf[6]);
        return (u0 + u1) + (u2 + u3);
#endif
    };

    // prologue: pair {beg, beg+1}
    unsigned pkA = pack[beg], pkB = pack[beg + 1];
    uint2 kv = *reinterpret_cast<const uint2*>(k8 + ((g ? pkB : pkA) & ~3u) + sub * 8);
    float scA = h2f_(scoresb[((pkA & ~3u) >> 2) + lane]);
    float scB = h2f_(scoresb[((pkB & ~3u) >> 2) + lane]);

    float m = -INFINITY, s = 0.f, acc = 0.f;

    for (int i = beg; i < end; i += 2) {
        int inext = (i + 2 < end) ? i + 2 : i;
        unsigned npA = pack[inext], npB = pack[inext + 1];
        uint2 nkv = *reinterpret_cast<const uint2*>(k8 + ((g ? npB : npA) & ~3u) + sub * 8);
        float nsA = h2f_(scoresb[((npA & ~3u) >> 2) + lane]);
        float nsB = h2f_(scoresb[((npB & ~3u) >> 2) + lane]);

        float a = dot8(kv);
        #pragma unroll
        for (int o = 1; o < 32; o <<= 1) a += __shfl_xor(a, o);
        float other = __shfl_xor(a, 32);
        float aA = (g ? other : a) + qsel(pkA);
        float aB = (g ? a : other) + qsel(pkB);
        if (i + 1 >= end) aB = -INFINITY;     // odd tail

        // T13 defer-max: rescale only when the running max grows by >11.5
        float bm = fmaxf(aA, aB);             // wave-uniform
        if (bm > m + 11.5f) {
            float c_ = exp2f(m - bm);         // first iter: exp2(-inf)=0
            s *= c_;
            acc *= c_;
            m = bm;
        }
        float w0 = exp2f(aA - m);
        float w1 = exp2f(aB - m);
        s += w0 + w1;
        acc = fmaf(w0, scA, fmaf(w1, scB, acc));

        pkA = npA; pkB = npB; kv = nkv; scA = nsA; scB = nsB;
    }
    out[(size_t)d * CC + lane] = acc / s;
}

extern "C" void kernel_launch(void* const* d_in, const int* in_sizes, int n_in,
                              void* d_out, int out_size, void* d_ws, size_t ws_size,
                              hipStream_t stream) {
    const float* embedding = (const float*)d_in[0];
    const float* scores    = (const float*)d_in[1];
    const int*   src       = (const int*)d_in[2];
    const int*   dst       = (const int*)d_in[3];
    const int*   typ       = (const int*)d_in[4];
    const float* W1  = (const float*)d_in[5];
    const float* b1  = (const float*)d_in[6];
    const float* W2  = (const float*)d_in[7];
    const float* b2  = (const float*)d_in[8];
    const float* ln_g = (const float*)d_in[9];
    const float* ln_b = (const float*)d_in[10];
    const float* Wl  = (const float*)d_in[11];
    const float* bl  = (const float*)d_in[12];
    const float* Wr  = (const float*)d_in[13];
    const float* br  = (const float*)d_in[14];
    const float* We  = (const float*)d_in[15];
    const float* be  = (const float*)d_in[16];
    const float* emb_table = (const float*)d_in[17];
    float* out = (float*)d_out;
    (void)in_sizes; (void)n_in; (void)out_size; (void)ws_size;

    // ---- workspace carve-up (256-aligned chunks) ----
    char* w = (char*)d_ws;
    auto take = [&](size_t bytes) {
        char* p = w;
        w += (bytes + 255) & ~(size_t)255;
        return p;
    };
    unsigned short* embA = (unsigned short*)take((size_t)NPAD * HH * 2);
    unsigned short* hpre = (unsigned short*)take((size_t)NPAD * HH * 2);
    // BIG buffer: Gch [NPAD][1024] f16 during the MLP; afterwards its first
    // NPAD*512B serve as qbuf [NPAD][256] f16 and the next NPAD*256B as the
    // fp8 k-buffer (Gch dead once GEMM2 reads it).
    unsigned short* Gch  = (unsigned short*)take((size_t)NPAD * 1024 * 2);
    unsigned short* qbuf = Gch;
    unsigned char*  k8   = (unsigned char*)(Gch + (size_t)NPAD * 256);
    unsigned short* W1T  = (unsigned short*)take((size_t)4 * HH * HH * 2);
    unsigned short* W2T  = (unsigned short*)take((size_t)HH * 4 * HH * 2);
    unsigned short* WlrT = (unsigned short*)take((size_t)512 * HH * 2);
    unsigned short* k2t  = (unsigned short*)take(2048);
    unsigned short* scoresb = (unsigned short*)take((size_t)NN * CC * 2);
    float*          uvec = (float*)take(512 * 4);
    float*          vvec = (float*)take(512 * 4);
    int*            cnt  = (int*)take((size_t)NPAD * 4);
    float*          st1  = (float*)take((size_t)NPAD * 4);
    float*          st2  = (float*)take((size_t)NPAD * 4);
    int*            offb = (int*)take((size_t)(NN + 1) * 4);
    int*            cur  = (int*)take((size_t)NN * 4);
    int*            bsum = (int*)take(256 * 4);
    unsigned int*   pack = (unsigned int*)take((size_t)EE * 4 + 64);

    hipMemsetAsync(cnt, 0, (size_t)3 * NPAD * 4, stream);

    // ---- one prep launch (conversions + transposes + k2 + u/v + histogram) ----
    prep_kernel<<<PB8, 256, 0, stream>>>(
        embedding, scores, W1, W2, Wl, Wr, ln_g, ln_b, bl, br, We, be,
        emb_table, dst,
        embA, scoresb, W1T, W2T, WlrT, k2t, uvec, vvec, cnt);

    // ---- GEMM1 (+ scan_part riding in 200 extra blocks) ----
    // grid (8, 391+25): GEMM flats [0, 3128), side blocks [3128, 3328)
    dim3 g1(8, 391 + 25);
    mfma_gemm<1, 1, false, false, 1><<<g1, 256, 0, stream>>>(
        embA, W1T, b1, Gch, nullptr, NN, HH, 4 * HH, 391,
        nullptr, nullptr, nullptr, nullptr, nullptr,
        cnt, offb, bsum, nullptr);

    // ---- GEMM2 (+ scan_sums in 2 extra blocks) ----
    dim3 g2(2, 391 + 1);
    mfma_gemm<0, 1, true, false, 2><<<g2, 256, 0, stream>>>(
        Gch, W2T, b2, hpre, nullptr, NN, 4 * HH, HH, 391,
        st1, st2, nullptr, nullptr, nullptr,
        nullptr, nullptr, bsum, nullptr);

    // ---- GEMMq: q|k1 projection + LN fold (+ scan_add in 196 extra blocks) ----
    dim3 gq(4, 391 + 49);
    mfma_gemm<0, 2, false, true, 3><<<gq, 256, 0, stream>>>(
        hpre, WlrT, vvec, qbuf, k8, NN, HH, 512, 391,
        nullptr, nullptr, st1, st2, uvec,
        nullptr, offb, bsum, cur);

    // ---- CSR fill, then fused edge phase ----
    fill_kernel<<<(EE + 255) / 256, 256, 0, stream>>>(src, dst, typ, cur, pack);
    fused_edge_kernel<<<(NN + 3) / 4, 256, 0, stream>>>(
        qbuf, k8, k2t, offb, pack, scoresb, out);
}